// Round 1
// baseline (651.599 us; speedup 1.0000x reference)
//
#include <hip/hip_runtime.h>
#include <math.h>

typedef unsigned short ushort_t;
typedef unsigned int uint_t;

#define NPIX 65536
#define EPS_ 1e-5f

__device__ __forceinline__ float bf2f(ushort_t u){ return __uint_as_float(((uint_t)u)<<16); }
__device__ __forceinline__ ushort_t f2bf(float f){
  uint_t u = __float_as_uint(f);
  uint_t r = (u + 0x7fffu + ((u>>16)&1u)) >> 16;
  return (ushort_t)r;
}
__device__ __forceinline__ float bflo(uint_t p){ return __uint_as_float(p<<16); }
__device__ __forceinline__ float bfhi(uint_t p){ return __uint_as_float(p & 0xffff0000u); }
__device__ __forceinline__ uint_t packbf(float a, float b){ return (uint_t)f2bf(a) | ((uint_t)f2bf(b)<<16); }

__device__ __forceinline__ float wave_sum(float v){
  #pragma unroll
  for(int m=32;m>=1;m>>=1) v += __shfl_xor(v, m, 64);
  return v;
}

// ---------------- K1: GN partial sums + row/col pools of raw u ----------------
__global__ __launch_bounds__(256) void k1_stats(const float* __restrict__ u,
    float* __restrict__ part, float* __restrict__ poolx, float* __restrict__ pooly){
  int blk = blockIdx.x; int b = blk>>6; int c = blk&63;
  int t = threadIdx.x; int lane = t&63; int w = t>>6;
  const float* up = u + ((size_t)(b*64+c))*NPIX;
  __shared__ float rp[256*4];
  __shared__ float red[8];
  float colsum=0.f, s1=0.f, s2=0.f;
  for(int i=0;i<256;i++){
    float v = up[i*256 + t];
    colsum += v; s1 += v; s2 += v*v;
    float rs = wave_sum(v);
    if(lane==0) rp[i*4 + w] = rs;
  }
  float a = wave_sum(s1), bq = wave_sum(s2);
  if(lane==0){ red[w]=a; red[4+w]=bq; }
  __syncthreads();
  if(t==0){
    part[(b*64+c)*2]   = red[0]+red[1]+red[2]+red[3];
    part[(b*64+c)*2+1] = red[4]+red[5]+red[6]+red[7];
  }
  float rowsum = rp[t*4]+rp[t*4+1]+rp[t*4+2]+rp[t*4+3];
  poolx[(b*256+t)*64 + c] = rowsum * (1.f/256.f);
  pooly[(b*256+t)*64 + c] = colsum * (1.f/256.f);
}

// ---------------- K2: finalize GroupNorm mean/rstd ----------------
__global__ void k2_fin(const float* __restrict__ part, float* __restrict__ gnmv){
  int t = threadIdx.x;
  if(t<4){
    float S1=0.f,S2=0.f;
    for(int c=0;c<64;c++){ S1 += part[(t*64+c)*2]; S2 += part[(t*64+c)*2+1]; }
    const float inv = 1.f/4194304.f;
    float m = S1*inv; float v = S2*inv - m*m;
    gnmv[t*2] = m; gnmv[t*2+1] = rsqrtf(v + EPS_);
  }
}

// ---------------- KT: transpose w_in_proj and out_w1 ----------------
__global__ __launch_bounds__(256) void kt_transpose(const float* __restrict__ wp,
    const float* __restrict__ w1, float* __restrict__ wpT, float* __restrict__ w1T){
  int t = threadIdx.x;
  for(int e=t;e<8192;e+=256){ int k=e>>7, oc=e&127; wpT[e] = wp[oc*64 + k]; }
  for(int e=t;e<8192;e+=256){ int k=e>>6, o=e&63;  w1T[e] = w1[o*128 + k]; }
}

// ---------------- K3: pooled path -> reducer (affine, w_to_in, win, LN, FFN) ----------------
__global__ __launch_bounds__(128) void k3_reduce(
    const float* __restrict__ poolx, const float* __restrict__ pooly,
    const float* __restrict__ gnmv,
    const float* __restrict__ gnw, const float* __restrict__ gnb,
    const float* __restrict__ w_to_in,
    const float* __restrict__ xwin, const float* __restrict__ xlg, const float* __restrict__ xlb,
    const float* __restrict__ xw1, const float* __restrict__ xw2, const float* __restrict__ xb2,
    const float* __restrict__ ywin, const float* __restrict__ ylg, const float* __restrict__ ylb,
    const float* __restrict__ yw1, const float* __restrict__ yw2, const float* __restrict__ yb2,
    float* __restrict__ ux, float* __restrict__ uy){
  int id = blockIdx.x;
  int side = id >> 10; int r = id & 1023; int b = r>>8; int i = r&255;
  const float* pool = side ? pooly : poolx;
  const float* win = side ? ywin : xwin;
  const float* lg  = side ? ylg  : xlg;
  const float* lb  = side ? ylb  : xlb;
  const float* w1  = side ? yw1  : xw1;
  const float* w2  = side ? yw2  : xw2;
  const float* b2  = side ? yb2  : xb2;
  float* outp = side ? uy : ux;
  int t = threadIdx.x;
  __shared__ float pn[64], t1[64], hh[64], f1[128];
  float mean = gnmv[b*2], rstd = gnmv[b*2+1];
  if(t<64){
    float pv = pool[(b*256+i)*64 + t];
    pn[t] = (pv - mean)*rstd*gnw[t] + gnb[t];
  }
  __syncthreads();
  if(t<64){
    float acc=0.f; const float* wr = w_to_in + t*64;
    #pragma unroll 8
    for(int c=0;c<64;c++) acc += pn[c]*wr[c];
    t1[t]=acc;
  }
  __syncthreads();
  if(t<64){
    float acc=0.f; const float* wr = win + t*64;
    #pragma unroll 8
    for(int c=0;c<64;c++) acc += t1[c]*wr[c];
    hh[t]=acc;
  }
  __syncthreads();
  if(t<64){
    float v = hh[t];
    float s = wave_sum(v);
    float ss = wave_sum(v*v);
    float m2 = s*(1.f/64.f);
    float var = ss*(1.f/64.f) - m2*m2;
    float rs2 = rsqrtf(var + EPS_);
    hh[t] = (v - m2)*rs2*lg[t] + lb[t];
  }
  __syncthreads();
  {
    float acc=0.f; const float* wr = w1 + t*64;
    #pragma unroll 8
    for(int c=0;c<64;c++) acc += hh[c]*wr[c];
    f1[t] = 0.5f*acc*(1.f + erff(acc*0.70710678118654752f));
  }
  __syncthreads();
  {
    float acc=0.f; const float* wr = w2 + t*128;
    #pragma unroll 8
    for(int j=0;j<128;j++) acc += f1[j]*wr[j];
    outp[(b*256+i)*128 + t] = acc + b2[t];
  }
}

// ---------------- K4: qk projection + RoPE -> q/k factor tensors ----------------
__global__ __launch_bounds__(128) void k4_qkrope(
    const float* __restrict__ ux, const float* __restrict__ uy,
    const float* __restrict__ wqkx, const float* __restrict__ wqky,
    float* __restrict__ qx, float* __restrict__ kxv,
    float* __restrict__ qy, float* __restrict__ kyv){
  int id = blockIdx.x;
  int side = id>>10; int r = id&1023; int b = r>>8; int i = r&255;
  const float* x = (side? uy:ux) + (b*256+i)*128;
  const float* wqk = side? wqky : wqkx;
  float* qo = side? qy : qx;
  float* ko = side? kyv : kxv;
  int t = threadIdx.x;
  __shared__ float xr[128];
  __shared__ float qk[512];
  xr[t] = x[t];
  __syncthreads();
  #pragma unroll
  for(int rr=0;rr<4;rr++){
    int o = rr*128 + t;
    const float4* wr = (const float4*)(wqk + o*128);
    float acc=0.f;
    #pragma unroll 8
    for(int c=0;c<32;c++){
      float4 wv = wr[c];
      float4 xv = *(const float4*)&xr[c*4];
      acc += wv.x*xv.x + wv.y*xv.y + wv.z*xv.z + wv.w*xv.w;
    }
    qk[o]=acc;
  }
  __syncthreads();
  float pos = (64.f/255.f)*(float)i;
  #pragma unroll
  for(int part=0;part<2;part++){
    float* dst = part? ko : qo;
    int base = part*256;
    for(int d2=t; d2<256; d2+=128){
      int h = d2>>6, dd = d2&63, t32 = dd&31;
      float f = pos * expf(-(float)t32*(9.210340371976184f/32.f));
      float cs = cosf(f), sn = sinf(f);
      float v = qk[base + h*64 + dd];
      float other = qk[base + h*64 + ((dd<32)? dd+32 : dd-32)];
      float rot = (dd<32)? -other : other;
      dst[((b*4+h)*256 + i)*64 + dd] = v*cs + rot*sn;
    }
  }
}

// ---------------- K6: GN-normalize + 1x1 conv -> u_phi (bf16, in d_out) ----------------
__global__ __launch_bounds__(256) void k6_phi(
    const float* __restrict__ u, const float* __restrict__ gnmv,
    const float* __restrict__ gnw, const float* __restrict__ gnb,
    const float* __restrict__ wpT, ushort_t* __restrict__ phi){
  int blk = blockIdx.x;
  int b = blk >> 8;
  int px = (blk & 255)*256 + threadIdx.x;
  float mean = gnmv[b*2], rstd = gnmv[b*2+1];
  const float* ub = u + (size_t)b*64*NPIX + px;
  #pragma unroll
  for(int half=0; half<2; ++half){
    float acc[64];
    #pragma unroll
    for(int o=0;o<64;o++) acc[o]=0.f;
    for(int k=0;k<64;k++){
      float sc = rstd*gnw[k];
      float sh = gnb[k] - mean*sc;
      float xn = ub[(size_t)k*NPIX]*sc + sh;
      const float* wr = wpT + k*128 + half*64;
      #pragma unroll
      for(int o=0;o<64;o++) acc[o] += xn*wr[o];
    }
    ushort_t* pp = phi + ((size_t)(b*128 + half*64))*NPIX + px;
    #pragma unroll
    for(int o=0;o<64;o++) pp[(size_t)o*NPIX] = f2bf(acc[o]);
  }
}

// ---------------- K7: fused low-rank double contraction per (b,h,c) ----------------
// out_c = Qx * (Kx^T * up_c * Ky) * Qy^T ; also InstanceNorm stats per channel.
struct __align__(16) SmemA {
  union {
    struct { float sK[16][68]; ushort_t sU[16][256]; } p1;
    float sQ[64][68];
  };
};

__global__ __launch_bounds__(256) void k7_heavy(
    const ushort_t* __restrict__ phi,
    const float* __restrict__ qx, const float* __restrict__ kxv,
    const float* __restrict__ qy, const float* __restrict__ kyv,
    ushort_t* __restrict__ up2, float* __restrict__ istat){
  int blk = blockIdx.x;
  int c = blk & 31; int h = (blk>>5)&3; int b = blk>>7;
  int bh = b*4 + h;
  int ch = h*32 + c;
  const uint_t* up_cu = (const uint_t*)(phi + ((size_t)(b*128 + ch))*NPIX);
  const float* kx_p = kxv + (size_t)bh*256*64;
  const float* ky_p = kyv + (size_t)bh*256*64;
  const float* qx_p = qx + (size_t)bh*256*64;
  const float* qy_p = qy + (size_t)bh*256*64;
  uint_t* out_cu = (uint_t*)(up2 + ((size_t)(b*128 + ch))*NPIX);

  __shared__ SmemA smA;
  __shared__ __align__(16) ushort_t sS1P[256][68];
  __shared__ __align__(16) ushort_t sCS[64][68];
  __shared__ float sRed[8];
  uint_t* sS1u = (uint_t*)&sS1P[0][0];
  uint_t* sCSu = (uint_t*)&sCS[0][0];
  uint_t* sUu  = (uint_t*)&smA.p1.sU[0][0];

  int t = threadIdx.x;

  // ---- Phase 1: S1T[m][d] = sum_j kxv[j][d] * up_c[j][m]  (store bf16)
  {
    int dg = t>>6, mg = t&63;
    float acc[16][4];
    #pragma unroll
    for(int q=0;q<16;q++){
      #pragma unroll
      for(int mm=0;mm<4;mm++) acc[q][mm]=0.f;
    }
    for(int jc=0;jc<16;jc++){
      #pragma unroll
      for(int r=0;r<4;r++){
        int e = r*256 + t; int jj = e>>6, d = e&63;
        smA.p1.sK[jj][d] = kx_p[(jc*16+jj)*64 + d];
      }
      #pragma unroll
      for(int r=0;r<8;r++){
        int e = r*256 + t; int jj = e>>7, mp = e&127;
        sUu[jj*128 + mp] = up_cu[(jc*16+jj)*128 + mp];
      }
      __syncthreads();
      #pragma unroll 4
      for(int jj=0;jj<16;jj++){
        uint2 uv = *(const uint2*)&sUu[jj*128 + mg*2];
        float b0 = bflo(uv.x), b1 = bfhi(uv.x), b2v = bflo(uv.y), b3 = bfhi(uv.y);
        #pragma unroll
        for(int q=0;q<4;q++){
          float4 a = *(const float4*)&smA.p1.sK[jj][dg*16 + q*4];
          acc[q*4+0][0] += a.x*b0; acc[q*4+0][1] += a.x*b1; acc[q*4+0][2] += a.x*b2v; acc[q*4+0][3] += a.x*b3;
          acc[q*4+1][0] += a.y*b0; acc[q*4+1][1] += a.y*b1; acc[q*4+1][2] += a.y*b2v; acc[q*4+1][3] += a.y*b3;
          acc[q*4+2][0] += a.z*b0; acc[q*4+2][1] += a.z*b1; acc[q*4+2][2] += a.z*b2v; acc[q*4+2][3] += a.z*b3;
          acc[q*4+3][0] += a.w*b0; acc[q*4+3][1] += a.w*b1; acc[q*4+3][2] += a.w*b2v; acc[q*4+3][3] += a.w*b3;
        }
      }
      __syncthreads();
    }
    #pragma unroll
    for(int mm=0;mm<4;mm++){
      int m = mg*4+mm;
      #pragma unroll
      for(int q=0;q<8;q++){
        sS1u[m*34 + dg*8 + q] = packbf(acc[2*q][mm], acc[2*q+1][mm]);
      }
    }
  }
  __syncthreads();

  // ---- Phase 2: core[d][e] = sum_m S1[d][m]*kyv[m][e]  (store bf16 in sCS)
  {
    int td = t&15, te = t>>4;
    float c2[4][4];
    #pragma unroll
    for(int a0=0;a0<4;a0++){
      #pragma unroll
      for(int b0=0;b0<4;b0++) c2[a0][b0]=0.f;
    }
    for(int mc=0;mc<4;mc++){
      #pragma unroll
      for(int r=0;r<16;r++){
        int e = r*256+t; int mm = e>>6, ee = e&63;
        smA.sQ[mm][ee] = ky_p[(mc*64+mm)*64 + ee];
      }
      __syncthreads();
      #pragma unroll 4
      for(int mm=0;mm<64;mm++){
        int m = mc*64+mm;
        uint2 sv = *(const uint2*)&sS1u[m*34 + td*2];
        float s0=bflo(sv.x), s1=bfhi(sv.x), s2=bflo(sv.y), s3=bfhi(sv.y);
        float4 kv = *(const float4*)&smA.sQ[mm][te*4];
        c2[0][0]+=s0*kv.x; c2[0][1]+=s0*kv.y; c2[0][2]+=s0*kv.z; c2[0][3]+=s0*kv.w;
        c2[1][0]+=s1*kv.x; c2[1][1]+=s1*kv.y; c2[1][2]+=s1*kv.z; c2[1][3]+=s1*kv.w;
        c2[2][0]+=s2*kv.x; c2[2][1]+=s2*kv.y; c2[2][2]+=s2*kv.z; c2[2][3]+=s2*kv.w;
        c2[3][0]+=s3*kv.x; c2[3][1]+=s3*kv.y; c2[3][2]+=s3*kv.z; c2[3][3]+=s3*kv.w;
      }
      __syncthreads();
    }
    #pragma unroll
    for(int dd=0;dd<4;dd++){
      int d = td*4+dd;
      sCSu[d*34 + te*2]   = packbf(c2[dd][0], c2[dd][1]);
      sCSu[d*34 + te*2+1] = packbf(c2[dd][2], c2[dd][3]);
    }
  }
  __syncthreads();

  // ---- Phase 3: P[i][e] = sum_d qx[i][d]*core[d][e] -> sS1P (bf16)
  {
    int ti = t&15, te = t>>4;
    for(int ic=0;ic<4;ic++){
      #pragma unroll
      for(int r=0;r<16;r++){
        int e = r*256+t; int ii = e>>6, d = e&63;
        smA.sQ[d][ii] = qx_p[(ic*64+ii)*64 + d];
      }
      __syncthreads();
      float p[4][4];
      #pragma unroll
      for(int a0=0;a0<4;a0++){
        #pragma unroll
        for(int b0=0;b0<4;b0++) p[a0][b0]=0.f;
      }
      #pragma unroll 4
      for(int d=0; d<64; d++){
        float4 qa = *(const float4*)&smA.sQ[d][ti*4];
        uint2 cv = *(const uint2*)&sCSu[d*34 + te*2];
        float e0=bflo(cv.x), e1=bfhi(cv.x), e2=bflo(cv.y), e3=bfhi(cv.y);
        p[0][0]+=qa.x*e0; p[0][1]+=qa.x*e1; p[0][2]+=qa.x*e2; p[0][3]+=qa.x*e3;
        p[1][0]+=qa.y*e0; p[1][1]+=qa.y*e1; p[1][2]+=qa.y*e2; p[1][3]+=qa.y*e3;
        p[2][0]+=qa.z*e0; p[2][1]+=qa.z*e1; p[2][2]+=qa.z*e2; p[2][3]+=qa.z*e3;
        p[3][0]+=qa.w*e0; p[3][1]+=qa.w*e1; p[3][2]+=qa.w*e2; p[3][3]+=qa.w*e3;
      }
      #pragma unroll
      for(int ii=0;ii<4;ii++){
        int i = ic*64 + ti*4 + ii;
        sS1u[i*34 + te*2]   = packbf(p[ii][0],p[ii][1]);
        sS1u[i*34 + te*2+1] = packbf(p[ii][2],p[ii][3]);
      }
      __syncthreads();
    }
  }

  // ---- Phase 4: out[i][l] = sum_e P[i][e]*qy[l][e]; stats; coalesced bf16 store
  float lsum=0.f, lssq=0.f;
  {
    int til = t&15, tlg = t>>4;
    for(int lt=0;lt<4;lt++){
      #pragma unroll
      for(int r=0;r<16;r++){
        int e = r*256+t; int ll = e>>6, ee = e&63;
        smA.sQ[ll][ee] = qy_p[(lt*64+ll)*64 + ee];
      }
      __syncthreads();
      for(int it=0;it<4;it++){
        float o[4][4];
        #pragma unroll
        for(int a0=0;a0<4;a0++){
          #pragma unroll
          for(int b0=0;b0<4;b0++) o[a0][b0]=0.f;
        }
        #pragma unroll 2
        for(int eq=0;eq<16;eq++){
          float pa[4][4]; float qb[4][4];
          #pragma unroll
          for(int r=0;r<4;r++){
            uint2 pv = *(const uint2*)&sS1u[(it*64 + til*4 + r)*34 + eq*2];
            pa[r][0]=bflo(pv.x); pa[r][1]=bfhi(pv.x); pa[r][2]=bflo(pv.y); pa[r][3]=bfhi(pv.y);
          }
          #pragma unroll
          for(int s=0;s<4;s++){
            float4 qv = *(const float4*)&smA.sQ[tlg*4+s][eq*4];
            qb[s][0]=qv.x; qb[s][1]=qv.y; qb[s][2]=qv.z; qb[s][3]=qv.w;
          }
          #pragma unroll
          for(int r=0;r<4;r++){
            #pragma unroll
            for(int s=0;s<4;s++)
              o[r][s] += pa[r][0]*qb[s][0] + pa[r][1]*qb[s][1] + pa[r][2]*qb[s][2] + pa[r][3]*qb[s][3];
          }
        }
        #pragma unroll
        for(int r=0;r<4;r++){
          #pragma unroll
          for(int s=0;s<4;s++){ float v=o[r][s]; lsum+=v; lssq+=v*v; }
          sCSu[(til*4+r)*34 + tlg*2]   = packbf(o[r][0],o[r][1]);
          sCSu[(til*4+r)*34 + tlg*2+1] = packbf(o[r][2],o[r][3]);
        }
        __syncthreads();
        #pragma unroll
        for(int rr=0;rr<8;rr++){
          int q = rr*256 + t; int row = q>>5, col = q&31;
          out_cu[(it*64+row)*128 + lt*32 + col] = sCSu[row*34 + col];
        }
        __syncthreads();
      }
    }
  }
  float a1 = wave_sum(lsum), a2 = wave_sum(lssq);
  int lane = t&63, w = t>>6;
  if(lane==0){ sRed[w]=a1; sRed[4+w]=a2; }
  __syncthreads();
  if(t==0){
    float S = sRed[0]+sRed[1]+sRed[2]+sRed[3];
    float SS = sRed[4]+sRed[5]+sRed[6]+sRed[7];
    float m = S*(1.f/65536.f);
    float var = SS*(1.f/65536.f) - m*m;
    istat[(b*128+ch)*2] = m;
    istat[(b*128+ch)*2+1] = rsqrtf(var + EPS_);
  }
}

// ---------------- KF: InstanceNorm + conv1-GELU-conv2 + residual ----------------
__global__ __launch_bounds__(256) void kf_out(
    const ushort_t* __restrict__ up2, const float* __restrict__ istat,
    const float* __restrict__ w1T, const float* __restrict__ w2,
    const float* __restrict__ u, float* __restrict__ out){
  int blk = blockIdx.x;
  int b = blk>>8;
  int px = (blk&255)*256 + threadIdx.x;
  const ushort_t* xp = up2 + (size_t)b*128*NPIX + px;
  float hid[64];
  #pragma unroll
  for(int o=0;o<64;o++) hid[o]=0.f;
  for(int k=0;k<128;k++){
    float m = istat[(b*128+k)*2], rs = istat[(b*128+k)*2+1];
    float x = (bf2f(xp[(size_t)k*NPIX]) - m)*rs;
    const float* wr = w1T + k*64;
    #pragma unroll
    for(int o=0;o<64;o++) hid[o] += x*wr[o];
  }
  #pragma unroll
  for(int o=0;o<64;o++){
    float hv = hid[o];
    hid[o] = 0.5f*hv*(1.f + erff(hv*0.70710678118654752f));
  }
  const float* ub = u + (size_t)b*64*NPIX + px;
  float* ob = out + (size_t)b*64*NPIX + px;
  for(int o2=0;o2<64;o2++){
    const float* wr = w2 + o2*64;
    float acc=0.f;
    #pragma unroll
    for(int o=0;o<64;o++) acc += hid[o]*wr[o];
    ob[(size_t)o2*NPIX] = acc + ub[(size_t)o2*NPIX];
  }
}

// ---------------- host launch ----------------
extern "C" void kernel_launch(void* const* d_in, const int* in_sizes, int n_in,
                              void* d_out, int out_size, void* d_ws, size_t ws_size,
                              hipStream_t stream) {
  (void)in_sizes; (void)n_in; (void)out_size; (void)ws_size;
  const float* u        = (const float*)d_in[0];
  const float* gnw      = (const float*)d_in[1];
  const float* gnb      = (const float*)d_in[2];
  const float* w_in_proj= (const float*)d_in[3];
  const float* w_to_in  = (const float*)d_in[4];
  const float* px_win   = (const float*)d_in[5];
  const float* px_ln_g  = (const float*)d_in[6];
  const float* px_ln_b  = (const float*)d_in[7];
  const float* px_w1    = (const float*)d_in[8];
  const float* px_w2    = (const float*)d_in[9];
  const float* px_b2    = (const float*)d_in[10];
  const float* py_win   = (const float*)d_in[11];
  const float* py_ln_g  = (const float*)d_in[12];
  const float* py_ln_b  = (const float*)d_in[13];
  const float* py_w1    = (const float*)d_in[14];
  const float* py_w2    = (const float*)d_in[15];
  const float* py_b2    = (const float*)d_in[16];
  const float* kx_wqk   = (const float*)d_in[17];
  const float* ky_wqk   = (const float*)d_in[18];
  const float* out_w1   = (const float*)d_in[19];
  const float* out_w2   = (const float*)d_in[20];
  float* out = (float*)d_out;

  float* fw = (float*)d_ws;
  float* part  = fw + 0;
  float* gnmv  = fw + 512;
  float* poolx = fw + 1024;
  float* pooly = fw + 66560;
  float* ux    = fw + 132096;
  float* uy    = fw + 263168;
  float* qx    = fw + 394240;
  float* kxv   = fw + 656384;
  float* qy    = fw + 918528;
  float* kyv   = fw + 1180672;
  float* istat = fw + 1442816;
  float* wpT   = fw + 1443840;
  float* w1T   = fw + 1452032;
  ushort_t* up2 = (ushort_t*)(fw + 1460224);
  ushort_t* phi = (ushort_t*)d_out;  // u_phi staged in d_out, consumed before final write

  k1_stats<<<dim3(256), dim3(256), 0, stream>>>(u, part, poolx, pooly);
  k2_fin<<<dim3(1), dim3(64), 0, stream>>>(part, gnmv);
  kt_transpose<<<dim3(1), dim3(256), 0, stream>>>(w_in_proj, out_w1, wpT, w1T);
  k3_reduce<<<dim3(2048), dim3(128), 0, stream>>>(poolx, pooly, gnmv, gnw, gnb, w_to_in,
      px_win, px_ln_g, px_ln_b, px_w1, px_w2, px_b2,
      py_win, py_ln_g, py_ln_b, py_w1, py_w2, py_b2, ux, uy);
  k4_qkrope<<<dim3(2048), dim3(128), 0, stream>>>(ux, uy, kx_wqk, ky_wqk, qx, kxv, qy, kyv);
  k6_phi<<<dim3(1024), dim3(256), 0, stream>>>(u, gnmv, gnw, gnb, wpT, phi);
  k7_heavy<<<dim3(512), dim3(256), 0, stream>>>(phi, qx, kxv, qy, kyv, up2, istat);
  kf_out<<<dim3(1024), dim3(256), 0, stream>>>(up2, istat, w1T, out_w2, u, out);
}

// Round 2
// 514.175 us; speedup vs baseline: 1.2673x; 1.2673x over previous
//
#include <hip/hip_runtime.h>
#include <math.h>

typedef unsigned short ushort_t;
typedef unsigned int uint_t;
typedef __attribute__((ext_vector_type(8))) short s8v;
typedef __attribute__((ext_vector_type(4))) float f4;

#define NPIX 65536
#define EPS_ 1e-5f

__device__ __forceinline__ float bf2f(ushort_t u){ return __uint_as_float(((uint_t)u)<<16); }
__device__ __forceinline__ ushort_t f2bf(float f){
  uint_t u = __float_as_uint(f);
  uint_t r = (u + 0x7fffu + ((u>>16)&1u)) >> 16;
  return (ushort_t)r;
}
__device__ __forceinline__ uint_t packbf(float a, float b){ return (uint_t)f2bf(a) | ((uint_t)f2bf(b)<<16); }

__device__ __forceinline__ f4 MFMA(s8v a, s8v b, f4 c){
  return __builtin_amdgcn_mfma_f32_16x16x32_bf16(a, b, c, 0, 0, 0);
}

__device__ __forceinline__ float wave_sum(float v){
  #pragma unroll
  for(int m=32;m>=1;m>>=1) v += __shfl_xor(v, m, 64);
  return v;
}

// ---------------- K1: GN partial sums + row/col pools of raw u ----------------
__global__ __launch_bounds__(256) void k1_stats(const float* __restrict__ u,
    float* __restrict__ part, float* __restrict__ poolx, float* __restrict__ pooly){
  int blk = blockIdx.x; int b = blk>>6; int c = blk&63;
  int t = threadIdx.x; int lane = t&63; int w = t>>6;
  const float* up = u + ((size_t)(b*64+c))*NPIX;
  __shared__ float rp[256*4];
  __shared__ float red[8];
  float colsum=0.f, s1=0.f, s2=0.f;
  for(int i=0;i<256;i++){
    float v = up[i*256 + t];
    colsum += v; s1 += v; s2 += v*v;
    float rs = wave_sum(v);
    if(lane==0) rp[i*4 + w] = rs;
  }
  float a = wave_sum(s1), bq = wave_sum(s2);
  if(lane==0){ red[w]=a; red[4+w]=bq; }
  __syncthreads();
  if(t==0){
    part[(b*64+c)*2]   = red[0]+red[1]+red[2]+red[3];
    part[(b*64+c)*2+1] = red[4]+red[5]+red[6]+red[7];
  }
  float rowsum = rp[t*4]+rp[t*4+1]+rp[t*4+2]+rp[t*4+3];
  poolx[(b*256+t)*64 + c] = rowsum * (1.f/256.f);
  pooly[(b*256+t)*64 + c] = colsum * (1.f/256.f);
}

// ---------------- K2: finalize GroupNorm mean/rstd ----------------
__global__ void k2_fin(const float* __restrict__ part, float* __restrict__ gnmv){
  int t = threadIdx.x;
  if(t<4){
    float S1=0.f,S2=0.f;
    for(int c=0;c<64;c++){ S1 += part[(t*64+c)*2]; S2 += part[(t*64+c)*2+1]; }
    const float inv = 1.f/4194304.f;
    float m = S1*inv; float v = S2*inv - m*m;
    gnmv[t*2] = m; gnmv[t*2+1] = rsqrtf(v + EPS_);
  }
}

// ---------------- KT: transpose w_in_proj and out_w1 ----------------
__global__ __launch_bounds__(256) void kt_transpose(const float* __restrict__ wp,
    const float* __restrict__ w1, float* __restrict__ wpT, float* __restrict__ w1T){
  int t = threadIdx.x;
  for(int e=t;e<8192;e+=256){ int k=e>>7, oc=e&127; wpT[e] = wp[oc*64 + k]; }
  for(int e=t;e<8192;e+=256){ int k=e>>6, o=e&63;  w1T[e] = w1[o*128 + k]; }
}

// ---------------- K3: pooled path -> reducer (affine, w_to_in, win, LN, FFN) ----------------
__global__ __launch_bounds__(128) void k3_reduce(
    const float* __restrict__ poolx, const float* __restrict__ pooly,
    const float* __restrict__ gnmv,
    const float* __restrict__ gnw, const float* __restrict__ gnb,
    const float* __restrict__ w_to_in,
    const float* __restrict__ xwin, const float* __restrict__ xlg, const float* __restrict__ xlb,
    const float* __restrict__ xw1, const float* __restrict__ xw2, const float* __restrict__ xb2,
    const float* __restrict__ ywin, const float* __restrict__ ylg, const float* __restrict__ ylb,
    const float* __restrict__ yw1, const float* __restrict__ yw2, const float* __restrict__ yb2,
    float* __restrict__ ux, float* __restrict__ uy){
  int id = blockIdx.x;
  int side = id >> 10; int r = id & 1023; int b = r>>8; int i = r&255;
  const float* pool = side ? pooly : poolx;
  const float* win = side ? ywin : xwin;
  const float* lg  = side ? ylg  : xlg;
  const float* lb  = side ? ylb  : xlb;
  const float* w1  = side ? yw1  : xw1;
  const float* w2  = side ? yw2  : xw2;
  const float* b2  = side ? yb2  : xb2;
  float* outp = side ? uy : ux;
  int t = threadIdx.x;
  __shared__ float pn[64], t1[64], hh[64], f1[128];
  float mean = gnmv[b*2], rstd = gnmv[b*2+1];
  if(t<64){
    float pv = pool[(b*256+i)*64 + t];
    pn[t] = (pv - mean)*rstd*gnw[t] + gnb[t];
  }
  __syncthreads();
  if(t<64){
    float acc=0.f; const float* wr = w_to_in + t*64;
    #pragma unroll 8
    for(int c=0;c<64;c++) acc += pn[c]*wr[c];
    t1[t]=acc;
  }
  __syncthreads();
  if(t<64){
    float acc=0.f; const float* wr = win + t*64;
    #pragma unroll 8
    for(int c=0;c<64;c++) acc += t1[c]*wr[c];
    hh[t]=acc;
  }
  __syncthreads();
  if(t<64){
    float v = hh[t];
    float s = wave_sum(v);
    float ss = wave_sum(v*v);
    float m2 = s*(1.f/64.f);
    float var = ss*(1.f/64.f) - m2*m2;
    float rs2 = rsqrtf(var + EPS_);
    hh[t] = (v - m2)*rs2*lg[t] + lb[t];
  }
  __syncthreads();
  {
    float acc=0.f; const float* wr = w1 + t*64;
    #pragma unroll 8
    for(int c=0;c<64;c++) acc += hh[c]*wr[c];
    f1[t] = 0.5f*acc*(1.f + erff(acc*0.70710678118654752f));
  }
  __syncthreads();
  {
    float acc=0.f; const float* wr = w2 + t*128;
    #pragma unroll 8
    for(int j=0;j<128;j++) acc += f1[j]*wr[j];
    outp[(b*256+i)*128 + t] = acc + b2[t];
  }
}

// ---------------- K4: qk projection + RoPE -> bf16 factor tensors ----------------
// Writes: Qx[i][d], Qy[l][e] (row-major, d contiguous) and KxT[d][j], KyT[e][m] (transposed)
__global__ __launch_bounds__(128) void k4_qkrope(
    const float* __restrict__ ux, const float* __restrict__ uy,
    const float* __restrict__ wqkx, const float* __restrict__ wqky,
    ushort_t* __restrict__ qxb, ushort_t* __restrict__ kxTb,
    ushort_t* __restrict__ qyb, ushort_t* __restrict__ kyTb){
  int id = blockIdx.x;
  int side = id>>10; int r = id&1023; int b = r>>8; int i = r&255;
  const float* x = (side? uy:ux) + (b*256+i)*128;
  const float* wqk = side? wqky : wqkx;
  ushort_t* qb = side? qyb : qxb;
  ushort_t* kTb = side? kyTb : kxTb;
  int t = threadIdx.x;
  __shared__ float xr[128];
  __shared__ float qk[512];
  xr[t] = x[t];
  __syncthreads();
  #pragma unroll
  for(int rr=0;rr<4;rr++){
    int o = rr*128 + t;
    const float4* wr = (const float4*)(wqk + o*128);
    float acc=0.f;
    #pragma unroll 8
    for(int c=0;c<32;c++){
      float4 wv = wr[c];
      float4 xv = *(const float4*)&xr[c*4];
      acc += wv.x*xv.x + wv.y*xv.y + wv.z*xv.z + wv.w*xv.w;
    }
    qk[o]=acc;
  }
  __syncthreads();
  float pos = (64.f/255.f)*(float)i;
  #pragma unroll
  for(int part=0;part<2;part++){
    int base = part*256;
    for(int d2=t; d2<256; d2+=128){
      int h = d2>>6, dd = d2&63, t32 = dd&31;
      float f = pos * expf(-(float)t32*(9.210340371976184f/32.f));
      float cs = cosf(f), sn = sinf(f);
      float v = qk[base + h*64 + dd];
      float other = qk[base + h*64 + ((dd<32)? dd+32 : dd-32)];
      float rot = (dd<32)? -other : other;
      float vout = v*cs + rot*sn;
      size_t bh = (size_t)(b*4 + h);
      if(part==0) qb[bh*16384 + i*64 + dd] = f2bf(vout);
      else        kTb[bh*16384 + dd*256 + i] = f2bf(vout);
    }
  }
}

// ---------------- K6: GN-normalize + 1x1 conv -> u_phi (bf16, in d_out) ----------------
__global__ __launch_bounds__(256) void k6_phi(
    const float* __restrict__ u, const float* __restrict__ gnmv,
    const float* __restrict__ gnw, const float* __restrict__ gnb,
    const float* __restrict__ wpT, ushort_t* __restrict__ phi){
  int blk = blockIdx.x;
  int b = blk >> 8;
  int px = (blk & 255)*256 + threadIdx.x;
  float mean = gnmv[b*2], rstd = gnmv[b*2+1];
  const float* ub = u + (size_t)b*64*NPIX + px;
  #pragma unroll
  for(int half=0; half<2; ++half){
    float acc[64];
    #pragma unroll
    for(int o=0;o<64;o++) acc[o]=0.f;
    for(int k=0;k<64;k++){
      float sc = rstd*gnw[k];
      float sh = gnb[k] - mean*sc;
      float xn = ub[(size_t)k*NPIX]*sc + sh;
      const float* wr = wpT + k*128 + half*64;
      #pragma unroll
      for(int o=0;o<64;o++) acc[o] += xn*wr[o];
    }
    ushort_t* pp = phi + ((size_t)(b*128 + half*64))*NPIX + px;
    #pragma unroll
    for(int o=0;o<64;o++) pp[(size_t)o*NPIX] = f2bf(acc[o]);
  }
}

// ---------------- K7: MFMA low-rank double contraction per (b,h,c) ----------------
// out_c = Qx * (Kx^T * (U_c * Ky)) * Qy^T; InstanceNorm stats per channel.
// Phase1: T1[j][e] = sum_m U[j][m]*Ky[m][e]      (A=U global, B=KyT global) -> sT1 (T1^T, bf16)
// Phase2: core[d][e] = sum_j KxT[d][j]*T1[j][e]  (A=KxT global, B=sT1)      -> regs -> sCT (core^T)
// Phase3: P^T[e][i] = sum_d coreT[e][d]*Qx[i][d] (A=sCT, B=Qx global)       -> sP (P, bf16)
// Phase4: out[i][l] = sum_e P[i][e]*Qy[l][e]     (A=sP, B=Qy global)        -> global bf16 + stats
__global__ __launch_bounds__(256) void k7_heavy(
    const ushort_t* __restrict__ phi,
    const ushort_t* __restrict__ qxb, const ushort_t* __restrict__ kxTb,
    const ushort_t* __restrict__ qyb, const ushort_t* __restrict__ kyTb,
    ushort_t* __restrict__ up2, float* __restrict__ istat){
  int blk = blockIdx.x;
  int c = blk & 31; int h = (blk>>5)&3; int b = blk>>7;
  int bh = b*4 + h; int ch = h*32 + c;
  const ushort_t* Uc  = phi + (size_t)(b*128 + ch)*NPIX;
  const ushort_t* KxT = kxTb + (size_t)bh*16384;
  const ushort_t* KyT = kyTb + (size_t)bh*16384;
  const ushort_t* Qx  = qxb + (size_t)bh*16384;
  const ushort_t* Qy  = qyb + (size_t)bh*16384;
  ushort_t* out_c = up2 + (size_t)(b*128 + ch)*NPIX;

  __shared__ __align__(16) ushort_t sT1[64*136];  // T1^T[e][j-chunk 128], stride 136
  __shared__ __align__(16) ushort_t sCT[64*72];   // core^T[e][d], stride 72
  __shared__ __align__(16) ushort_t sP[256*72];   // P[i][e], stride 72
  __shared__ float sRed[8];

  int t = threadIdx.x; int w = t>>6; int lane = t&63; int lr = lane&15; int lg = lane>>4;
  const f4 fz = {0.f,0.f,0.f,0.f};
  f4 cacc[4];
  #pragma unroll
  for(int et=0;et<4;et++) cacc[et]=fz;

  for(int jc=0;jc<2;jc++){
    // ---- Phase 1 (j-chunk): wave w covers j in [jc*128 + w*32, +32)
    f4 acc[2][4];
    #pragma unroll
    for(int jt=0;jt<2;jt++)
      #pragma unroll
      for(int et=0;et<4;et++) acc[jt][et]=fz;
    int jb = jc*128 + w*32;
    #pragma unroll
    for(int km=0;km<8;km++){
      s8v a0 = *(const s8v*)(Uc + (jb+lr)*256 + km*32 + lg*8);
      s8v a1 = *(const s8v*)(Uc + (jb+16+lr)*256 + km*32 + lg*8);
      #pragma unroll
      for(int et=0;et<4;et++){
        s8v bv = *(const s8v*)(KyT + (et*16+lr)*256 + km*32 + lg*8);
        acc[0][et] = MFMA(a0,bv,acc[0][et]);
        acc[1][et] = MFMA(a1,bv,acc[1][et]);
      }
    }
    // store T1^T chunk: lane holds T1[j = jb+jt*16+lg*4+r][e = et*16+lr]
    #pragma unroll
    for(int jt=0;jt<2;jt++){
      #pragma unroll
      for(int et=0;et<4;et++){
        f4 v = acc[jt][et];
        uint2 pk; pk.x = packbf(v.x,v.y); pk.y = packbf(v.z,v.w);
        *(uint2*)&sT1[(et*16+lr)*136 + w*32 + jt*16 + lg*4] = pk;
      }
    }
    __syncthreads();
    // ---- Phase 2 accumulate: wave w covers d in [w*16, +16)
    #pragma unroll
    for(int kj=0;kj<4;kj++){
      s8v a = *(const s8v*)(KxT + (w*16+lr)*256 + jc*128 + kj*32 + lg*8);
      #pragma unroll
      for(int et=0;et<4;et++){
        s8v bv = *(const s8v*)&sT1[(et*16+lr)*136 + kj*32 + lg*8];
        cacc[et] = MFMA(a,bv,cacc[et]);
      }
    }
    __syncthreads();
  }
  // store core^T: lane holds core[d = w*16+lg*4+r][e = et*16+lr]
  #pragma unroll
  for(int et=0;et<4;et++){
    f4 v = cacc[et];
    uint2 pk; pk.x=packbf(v.x,v.y); pk.y=packbf(v.z,v.w);
    *(uint2*)&sCT[(et*16+lr)*72 + w*16 + lg*4] = pk;
  }
  __syncthreads();
  // ---- Phase 3: P^T[e][i], wave w covers i in [w*64, +64)
  {
    s8v aF[4][2];
    #pragma unroll
    for(int me=0;me<4;me++)
      #pragma unroll
      for(int kd=0;kd<2;kd++)
        aF[me][kd] = *(const s8v*)&sCT[(me*16+lr)*72 + kd*32 + lg*8];
    #pragma unroll
    for(int it=0;it<4;it++){
      s8v b0 = *(const s8v*)(Qx + (w*64+it*16+lr)*64 + lg*8);
      s8v b1 = *(const s8v*)(Qx + (w*64+it*16+lr)*64 + 32 + lg*8);
      #pragma unroll
      for(int me=0;me<4;me++){
        f4 pv = MFMA(aF[me][0], b0, fz);
        pv = MFMA(aF[me][1], b1, pv);
        // lane holds P^T[e = me*16+lg*4+r][i = w*64+it*16+lr] -> store P[i][e]
        uint2 pk; pk.x=packbf(pv.x,pv.y); pk.y=packbf(pv.z,pv.w);
        *(uint2*)&sP[(w*64+it*16+lr)*72 + me*16 + lg*4] = pk;
      }
    }
  }
  __syncthreads();
  // ---- Phase 4: out[i][l], wave w covers i in [w*64, +64), loop l-tiles
  float lsum=0.f, lssq=0.f;
  {
    s8v aP[4][2];
    #pragma unroll
    for(int it=0;it<4;it++)
      #pragma unroll
      for(int ke=0;ke<2;ke++)
        aP[it][ke] = *(const s8v*)&sP[(w*64+it*16+lr)*72 + ke*32 + lg*8];
    for(int lt=0;lt<4;lt++){
      s8v bq[4][2];
      #pragma unroll
      for(int nt=0;nt<4;nt++)
        #pragma unroll
        for(int ke=0;ke<2;ke++)
          bq[nt][ke] = *(const s8v*)(Qy + (lt*64+nt*16+lr)*64 + ke*32 + lg*8);
      #pragma unroll
      for(int it=0;it<4;it++){
        #pragma unroll
        for(int nt=0;nt<4;nt++){
          f4 o = MFMA(aP[it][0], bq[nt][0], fz);
          o = MFMA(aP[it][1], bq[nt][1], o);
          #pragma unroll
          for(int r=0;r<4;r++){
            float val = o[r];
            lsum += val; lssq += val*val;
            out_c[(size_t)(w*64 + it*16 + lg*4 + r)*256 + lt*64 + nt*16 + lr] = f2bf(val);
          }
        }
      }
    }
  }
  float a1 = wave_sum(lsum), a2 = wave_sum(lssq);
  if(lane==0){ sRed[w]=a1; sRed[4+w]=a2; }
  __syncthreads();
  if(t==0){
    float S = sRed[0]+sRed[1]+sRed[2]+sRed[3];
    float SS = sRed[4]+sRed[5]+sRed[6]+sRed[7];
    float m = S*(1.f/65536.f);
    float var = SS*(1.f/65536.f) - m*m;
    istat[(b*128+ch)*2] = m;
    istat[(b*128+ch)*2+1] = rsqrtf(var + EPS_);
  }
}

// ---------------- KF: InstanceNorm + conv1-GELU-conv2 + residual ----------------
__global__ __launch_bounds__(256) void kf_out(
    const ushort_t* __restrict__ up2, const float* __restrict__ istat,
    const float* __restrict__ w1T, const float* __restrict__ w2,
    const float* __restrict__ u, float* __restrict__ out){
  int blk = blockIdx.x;
  int b = blk>>8;
  int px = (blk&255)*256 + threadIdx.x;
  const ushort_t* xp = up2 + (size_t)b*128*NPIX + px;
  float hid[64];
  #pragma unroll
  for(int o=0;o<64;o++) hid[o]=0.f;
  for(int k=0;k<128;k++){
    float m = istat[(b*128+k)*2], rs = istat[(b*128+k)*2+1];
    float x = (bf2f(xp[(size_t)k*NPIX]) - m)*rs;
    const float* wr = w1T + k*64;
    #pragma unroll
    for(int o=0;o<64;o++) hid[o] += x*wr[o];
  }
  #pragma unroll
  for(int o=0;o<64;o++){
    float hv = hid[o];
    hid[o] = 0.5f*hv*(1.f + erff(hv*0.70710678118654752f));
  }
  const float* ub = u + (size_t)b*64*NPIX + px;
  float* ob = out + (size_t)b*64*NPIX + px;
  for(int o2=0;o2<64;o2++){
    const float* wr = w2 + o2*64;
    float acc=0.f;
    #pragma unroll
    for(int o=0;o<64;o++) acc += hid[o]*wr[o];
    ob[(size_t)o2*NPIX] = acc + ub[(size_t)o2*NPIX];
  }
}

// ---------------- host launch ----------------
extern "C" void kernel_launch(void* const* d_in, const int* in_sizes, int n_in,
                              void* d_out, int out_size, void* d_ws, size_t ws_size,
                              hipStream_t stream) {
  (void)in_sizes; (void)n_in; (void)out_size; (void)ws_size;
  const float* u        = (const float*)d_in[0];
  const float* gnw      = (const float*)d_in[1];
  const float* gnb      = (const float*)d_in[2];
  const float* w_in_proj= (const float*)d_in[3];
  const float* w_to_in  = (const float*)d_in[4];
  const float* px_win   = (const float*)d_in[5];
  const float* px_ln_g  = (const float*)d_in[6];
  const float* px_ln_b  = (const float*)d_in[7];
  const float* px_w1    = (const float*)d_in[8];
  const float* px_w2    = (const float*)d_in[9];
  const float* px_b2    = (const float*)d_in[10];
  const float* py_win   = (const float*)d_in[11];
  const float* py_ln_g  = (const float*)d_in[12];
  const float* py_ln_b  = (const float*)d_in[13];
  const float* py_w1    = (const float*)d_in[14];
  const float* py_w2    = (const float*)d_in[15];
  const float* py_b2    = (const float*)d_in[16];
  const float* kx_wqk   = (const float*)d_in[17];
  const float* ky_wqk   = (const float*)d_in[18];
  const float* out_w1   = (const float*)d_in[19];
  const float* out_w2   = (const float*)d_in[20];
  float* out = (float*)d_out;

  float* fw = (float*)d_ws;
  float* part  = fw + 0;
  float* gnmv  = fw + 512;
  float* poolx = fw + 1024;
  float* pooly = fw + 66560;
  float* ux    = fw + 132096;
  float* uy    = fw + 263168;
  float* istat = fw + 394240;
  float* wpT   = fw + 395264;
  float* w1T   = fw + 403456;
  ushort_t* qxb  = (ushort_t*)(fw + 411648);
  ushort_t* qyb  = (ushort_t*)(fw + 542720);
  ushort_t* kxTb = (ushort_t*)(fw + 673792);
  ushort_t* kyTb = (ushort_t*)(fw + 804864);
  ushort_t* up2  = (ushort_t*)(fw + 935936);
  ushort_t* phi = (ushort_t*)d_out;  // u_phi staged in d_out, consumed before final write

  k1_stats<<<dim3(256), dim3(256), 0, stream>>>(u, part, poolx, pooly);
  k2_fin<<<dim3(1), dim3(64), 0, stream>>>(part, gnmv);
  kt_transpose<<<dim3(1), dim3(256), 0, stream>>>(w_in_proj, out_w1, wpT, w1T);
  k3_reduce<<<dim3(2048), dim3(128), 0, stream>>>(poolx, pooly, gnmv, gnw, gnb, w_to_in,
      px_win, px_ln_g, px_ln_b, px_w1, px_w2, px_b2,
      py_win, py_ln_g, py_ln_b, py_w1, py_w2, py_b2, ux, uy);
  k4_qkrope<<<dim3(2048), dim3(128), 0, stream>>>(ux, uy, kx_wqk, ky_wqk, qxb, kxTb, qyb, kyTb);
  k6_phi<<<dim3(1024), dim3(256), 0, stream>>>(u, gnmv, gnw, gnb, wpT, phi);
  k7_heavy<<<dim3(512), dim3(256), 0, stream>>>(phi, qxb, kxTb, qyb, kyTb, up2, istat);
  kf_out<<<dim3(1024), dim3(256), 0, stream>>>(up2, istat, w1T, out_w2, u, out);
}

// Round 3
// 258.205 us; speedup vs baseline: 2.5236x; 1.9913x over previous
//
#include <hip/hip_runtime.h>
#include <math.h>

typedef unsigned short ushort_t;
typedef unsigned int uint_t;
typedef __attribute__((ext_vector_type(8))) short s8v;
typedef __attribute__((ext_vector_type(4))) float f4;

#define NPIX 65536
#define EPS_ 1e-5f

__device__ __forceinline__ float bf2f(ushort_t u){ return __uint_as_float(((uint_t)u)<<16); }
__device__ __forceinline__ ushort_t f2bf(float f){
  uint_t u = __float_as_uint(f);
  uint_t r = (u + 0x7fffu + ((u>>16)&1u)) >> 16;
  return (ushort_t)r;
}
__device__ __forceinline__ float bflo(uint_t p){ return __uint_as_float(p<<16); }
__device__ __forceinline__ float bfhi(uint_t p){ return __uint_as_float(p & 0xffff0000u); }
__device__ __forceinline__ uint_t packbf(float a, float b){ return (uint_t)f2bf(a) | ((uint_t)f2bf(b)<<16); }

__device__ __forceinline__ f4 MFMA(s8v a, s8v b, f4 c){
  return __builtin_amdgcn_mfma_f32_16x16x32_bf16(a, b, c, 0, 0, 0);
}

__device__ __forceinline__ float wave_sum(float v){
  #pragma unroll
  for(int m=32;m>=1;m>>=1) v += __shfl_xor(v, m, 64);
  return v;
}

// ---------------- K1: GN partial sums + partial col sums + row pools ----------------
// grid 1024: b = blk>>8, c = (blk>>2)&63, iq = blk&3 (64-row slab)
__global__ __launch_bounds__(256) void k1_stats(const float* __restrict__ u,
    float* __restrict__ part, float* __restrict__ pc, float* __restrict__ poolx){
  int blk = blockIdx.x; int b = blk>>8; int c = (blk>>2)&63; int iq = blk&3;
  int t = threadIdx.x; int lane = t&63; int w = t>>6;
  const float* up = u + ((size_t)(b*64+c))*NPIX + iq*64*256;
  __shared__ float red[8];
  // pass A: per-column partial sums (coalesced) + GN sums
  float cs=0.f, ss=0.f;
  for(int r=0;r<64;r++){
    float v = up[r*256 + t];
    cs += v; ss += v*v;
  }
  pc[((b*64+c)*4 + iq)*256 + t] = cs;
  float a1 = wave_sum(cs), a2 = wave_sum(ss);
  if(lane==0){ red[w]=a1; red[4+w]=a2; }
  __syncthreads();
  if(t==0){
    part[((b*64+c)*4+iq)*2]   = red[0]+red[1]+red[2]+red[3];
    part[((b*64+c)*4+iq)*2+1] = red[4]+red[5]+red[6]+red[7];
  }
  // pass B: row sums (tile is cache-hot)
  int r = t>>2, ck = t&3;
  const float* rp = up + r*256 + ck*64;
  float s=0.f;
  #pragma unroll 4
  for(int j=0;j<16;j++){
    float4 v4 = *(const float4*)(rp + j*4);
    s += v4.x + v4.y + v4.z + v4.w;
  }
  s += __shfl_xor(s, 1, 64);
  s += __shfl_xor(s, 2, 64);
  if(ck==0) poolx[(b*256 + iq*64 + r)*64 + c] = s * (1.f/256.f);
}

// ---------------- K2: finalize GroupNorm mean/rstd ----------------
__global__ void k2_fin(const float* __restrict__ part, float* __restrict__ gnmv){
  int t = threadIdx.x; int b = t>>6; int i = t&63;
  float S1=0.f, S2=0.f;
  #pragma unroll
  for(int q=0;q<4;q++){
    S1 += part[((b*64+i)*4+q)*2];
    S2 += part[((b*64+i)*4+q)*2+1];
  }
  S1 = wave_sum(S1); S2 = wave_sum(S2);
  if(i==0){
    const float inv = 1.f/4194304.f;
    float m = S1*inv; float v = S2*inv - m*m;
    gnmv[b*2] = m; gnmv[b*2+1] = rsqrtf(v + EPS_);
  }
}

// ---------------- K2b: finalize pooly from partial col sums ----------------
__global__ __launch_bounds__(256) void k2b_pool(const float* __restrict__ pc,
    float* __restrict__ pooly){
  int blk = blockIdx.x; int b = blk>>6; int c = blk&63;
  int t = threadIdx.x;
  const float* p = pc + ((size_t)(b*64+c))*4*256 + t;
  float s = p[0] + p[256] + p[512] + p[768];
  pooly[(b*256+t)*64 + c] = s * (1.f/256.f);
}

// ---------------- K8a: fold GN into w_in_proj (per batch) + w2 bf16 ----------------
__global__ __launch_bounds__(256) void k8a_fold(const float* __restrict__ gnmv,
    const float* __restrict__ gnw, const float* __restrict__ gnb,
    const float* __restrict__ w_in_proj, const float* __restrict__ out_w2,
    ushort_t* __restrict__ wpb, float* __restrict__ c0g, ushort_t* __restrict__ w2b){
  int b = blockIdx.x; int t = threadIdx.x;
  __shared__ float scs[64], shs[64];
  if(t<64){
    float mean = gnmv[b*2], rstd = gnmv[b*2+1];
    float sc = rstd*gnw[t];
    scs[t] = sc; shs[t] = gnb[t] - mean*sc;
  }
  __syncthreads();
  int oc = t>>1, h = t&1;
  float c0 = 0.f;
  for(int k=0;k<32;k++){
    int ch = h*32 + k;
    float wv = w_in_proj[oc*64 + ch];
    wpb[((size_t)b*128 + oc)*64 + ch] = f2bf(wv*scs[ch]);
    c0 += wv*shs[ch];
  }
  c0 += __shfl_xor(c0, 1, 64);
  if(h==0) c0g[b*128 + oc] = c0;
  if(b==0){
    for(int e=t;e<4096;e+=256) w2b[e] = f2bf(out_w2[e]);
  }
}

// ---------------- K8b: fold InstanceNorm into out_w1 (per batch) ----------------
__global__ void k8b_fold(const float* __restrict__ istat,
    const float* __restrict__ out_w1, ushort_t* __restrict__ W1b,
    float* __restrict__ bias1){
  int b = blockIdx.x; int t = threadIdx.x;  // 64 threads
  __shared__ float ms[128], rss[128];
  ms[t] = istat[(b*128+t)*2];       rss[t] = istat[(b*128+t)*2+1];
  ms[64+t] = istat[(b*128+64+t)*2]; rss[64+t] = istat[(b*128+64+t)*2+1];
  __syncthreads();
  float bias = 0.f;
  for(int ch=0;ch<128;ch++){
    float wv = out_w1[t*128 + ch];
    float wr = wv*rss[ch];
    W1b[((size_t)b*64 + t)*128 + ch] = f2bf(wr);
    bias += wr*ms[ch];
  }
  bias1[b*64 + t] = bias;
}

// ---------------- K3: pooled path -> reducer (unchanged) ----------------
__global__ __launch_bounds__(128) void k3_reduce(
    const float* __restrict__ poolx, const float* __restrict__ pooly,
    const float* __restrict__ gnmv,
    const float* __restrict__ gnw, const float* __restrict__ gnb,
    const float* __restrict__ w_to_in,
    const float* __restrict__ xwin, const float* __restrict__ xlg, const float* __restrict__ xlb,
    const float* __restrict__ xw1, const float* __restrict__ xw2, const float* __restrict__ xb2,
    const float* __restrict__ ywin, const float* __restrict__ ylg, const float* __restrict__ ylb,
    const float* __restrict__ yw1, const float* __restrict__ yw2, const float* __restrict__ yb2,
    float* __restrict__ ux, float* __restrict__ uy){
  int id = blockIdx.x;
  int side = id >> 10; int r = id & 1023; int b = r>>8; int i = r&255;
  const float* pool = side ? pooly : poolx;
  const float* win = side ? ywin : xwin;
  const float* lg  = side ? ylg  : xlg;
  const float* lb  = side ? ylb  : xlb;
  const float* w1  = side ? yw1  : xw1;
  const float* w2  = side ? yw2  : xw2;
  const float* b2  = side ? yb2  : xb2;
  float* outp = side ? uy : ux;
  int t = threadIdx.x;
  __shared__ float pn[64], t1[64], hh[64], f1[128];
  float mean = gnmv[b*2], rstd = gnmv[b*2+1];
  if(t<64){
    float pv = pool[(b*256+i)*64 + t];
    pn[t] = (pv - mean)*rstd*gnw[t] + gnb[t];
  }
  __syncthreads();
  if(t<64){
    float acc=0.f; const float* wr = w_to_in + t*64;
    #pragma unroll 8
    for(int c=0;c<64;c++) acc += pn[c]*wr[c];
    t1[t]=acc;
  }
  __syncthreads();
  if(t<64){
    float acc=0.f; const float* wr = win + t*64;
    #pragma unroll 8
    for(int c=0;c<64;c++) acc += t1[c]*wr[c];
    hh[t]=acc;
  }
  __syncthreads();
  if(t<64){
    float v = hh[t];
    float s = wave_sum(v);
    float ss = wave_sum(v*v);
    float m2 = s*(1.f/64.f);
    float var = ss*(1.f/64.f) - m2*m2;
    float rs2 = rsqrtf(var + EPS_);
    hh[t] = (v - m2)*rs2*lg[t] + lb[t];
  }
  __syncthreads();
  {
    float acc=0.f; const float* wr = w1 + t*64;
    #pragma unroll 8
    for(int c=0;c<64;c++) acc += hh[c]*wr[c];
    f1[t] = 0.5f*acc*(1.f + erff(acc*0.70710678118654752f));
  }
  __syncthreads();
  {
    float acc=0.f; const float* wr = w2 + t*128;
    #pragma unroll 8
    for(int j=0;j<128;j++) acc += f1[j]*wr[j];
    outp[(b*256+i)*128 + t] = acc + b2[t];
  }
}

// ---------------- K4: qk projection + RoPE -> bf16 factor tensors (unchanged) ----------------
__global__ __launch_bounds__(128) void k4_qkrope(
    const float* __restrict__ ux, const float* __restrict__ uy,
    const float* __restrict__ wqkx, const float* __restrict__ wqky,
    ushort_t* __restrict__ qxb, ushort_t* __restrict__ kxTb,
    ushort_t* __restrict__ qyb, ushort_t* __restrict__ kyTb){
  int id = blockIdx.x;
  int side = id>>10; int r = id&1023; int b = r>>8; int i = r&255;
  const float* x = (side? uy:ux) + (b*256+i)*128;
  const float* wqk = side? wqky : wqkx;
  ushort_t* qb = side? qyb : qxb;
  ushort_t* kTb = side? kyTb : kxTb;
  int t = threadIdx.x;
  __shared__ float xr[128];
  __shared__ float qk[512];
  xr[t] = x[t];
  __syncthreads();
  #pragma unroll
  for(int rr=0;rr<4;rr++){
    int o = rr*128 + t;
    const float4* wr = (const float4*)(wqk + o*128);
    float acc=0.f;
    #pragma unroll 8
    for(int c=0;c<32;c++){
      float4 wv = wr[c];
      float4 xv = *(const float4*)&xr[c*4];
      acc += wv.x*xv.x + wv.y*xv.y + wv.z*xv.z + wv.w*xv.w;
    }
    qk[o]=acc;
  }
  __syncthreads();
  float pos = (64.f/255.f)*(float)i;
  #pragma unroll
  for(int part=0;part<2;part++){
    int base = part*256;
    for(int d2=t; d2<256; d2+=128){
      int h = d2>>6, dd = d2&63, t32 = dd&31;
      float f = pos * expf(-(float)t32*(9.210340371976184f/32.f));
      float cs = cosf(f), sn = sinf(f);
      float v = qk[base + h*64 + dd];
      float other = qk[base + h*64 + ((dd<32)? dd+32 : dd-32)];
      float rot = (dd<32)? -other : other;
      float vout = v*cs + rot*sn;
      size_t bh = (size_t)(b*4 + h);
      if(part==0) qb[bh*16384 + i*64 + dd] = f2bf(vout);
      else        kTb[bh*16384 + dd*256 + i] = f2bf(vout);
    }
  }
}

// ---------------- K6: MFMA 1x1 conv u -> u_phi (GN folded into weights) ----------------
// grid 2048: b = blk>>9, pix tile of 128
__global__ __launch_bounds__(256) void k6_phi(
    const float* __restrict__ u, const ushort_t* __restrict__ wpb,
    const float* __restrict__ c0g, ushort_t* __restrict__ phi){
  int blk = blockIdx.x;
  int b = blk>>9; int pix0 = (blk&511)<<7;
  __shared__ __align__(16) ushort_t sm[128*136];
  int t = threadIdx.x; int lane = t&63; int w = t>>6; int lr = lane&15; int lg = lane>>4;
  // stage u tile -> bf16 sIn[64ch][132]
  {
    int ch = t>>5; int px = (t&31)*4;
    #pragma unroll
    for(int it=0; it<8; it++){
      int c = it*8 + ch;
      float4 v = *(const float4*)(u + ((size_t)(b*64+c))*NPIX + pix0 + px);
      uint2 pk; pk.x = packbf(v.x, v.y); pk.y = packbf(v.z, v.w);
      *(uint2*)&sm[c*132 + px] = pk;
    }
  }
  __syncthreads();
  // GEMM: D[pix 128][oc 128] = sum_ch un[pix][ch]*W'[oc][ch]
  const ushort_t* wb = wpb + (size_t)b*128*64;
  f4 acc[2][8];
  #pragma unroll
  for(int it=0;it<2;it++)
    #pragma unroll
    for(int nt=0;nt<8;nt++){
      float cv = c0g[b*128 + nt*16 + lr];
      f4 ci = {cv,cv,cv,cv};
      acc[it][nt] = ci;
    }
  #pragma unroll
  for(int kc=0;kc<2;kc++){
    s8v bf[8];
    #pragma unroll
    for(int nt=0;nt<8;nt++)
      bf[nt] = *(const s8v*)(wb + (nt*16+lr)*64 + kc*32 + lg*8);
    #pragma unroll
    for(int it=0;it<2;it++){
      int pix = w*32 + it*16 + lr;
      s8v a;
      #pragma unroll
      for(int j=0;j<8;j++) a[j] = (short)sm[(kc*32+lg*8+j)*132 + pix];
      #pragma unroll
      for(int nt=0;nt<8;nt++)
        acc[it][nt] = MFMA(a, bf[nt], acc[it][nt]);
    }
  }
  __syncthreads();
  // pack to sOut[128oc][136]
  #pragma unroll
  for(int it=0;it<2;it++)
    #pragma unroll
    for(int nt=0;nt<8;nt++){
      f4 v = acc[it][nt];
      uint2 pk; pk.x = packbf(v.x,v.y); pk.y = packbf(v.z,v.w);
      *(uint2*)&sm[(nt*16+lr)*136 + w*32 + it*16 + lg*4] = pk;
    }
  __syncthreads();
  // coalesced store
  {
    int oc = t>>4; int px = (t&15)*8;
    #pragma unroll
    for(int it=0;it<8;it++){
      int o = it*16 + oc;
      *(uint4*)(phi + ((size_t)(b*128+o))*NPIX + pix0 + px) = *(const uint4*)&sm[o*136 + px];
    }
  }
}

// ---------------- K7: MFMA low-rank double contraction per (b,h,c) (unchanged) ----------------
__global__ __launch_bounds__(256) void k7_heavy(
    const ushort_t* __restrict__ phi,
    const ushort_t* __restrict__ qxb, const ushort_t* __restrict__ kxTb,
    const ushort_t* __restrict__ qyb, const ushort_t* __restrict__ kyTb,
    ushort_t* __restrict__ up2, float* __restrict__ istat){
  int blk = blockIdx.x;
  int c = blk & 31; int h = (blk>>5)&3; int b = blk>>7;
  int bh = b*4 + h; int ch = h*32 + c;
  const ushort_t* Uc  = phi + (size_t)(b*128 + ch)*NPIX;
  const ushort_t* KxT = kxTb + (size_t)bh*16384;
  const ushort_t* KyT = kyTb + (size_t)bh*16384;
  const ushort_t* Qx  = qxb + (size_t)bh*16384;
  const ushort_t* Qy  = qyb + (size_t)bh*16384;
  ushort_t* out_c = up2 + (size_t)(b*128 + ch)*NPIX;

  __shared__ __align__(16) ushort_t sT1[64*136];
  __shared__ __align__(16) ushort_t sCT[64*72];
  __shared__ __align__(16) ushort_t sP[256*72];
  __shared__ float sRed[8];

  int t = threadIdx.x; int w = t>>6; int lane = t&63; int lr = lane&15; int lg = lane>>4;
  const f4 fz = {0.f,0.f,0.f,0.f};
  f4 cacc[4];
  #pragma unroll
  for(int et=0;et<4;et++) cacc[et]=fz;

  for(int jc=0;jc<2;jc++){
    f4 acc[2][4];
    #pragma unroll
    for(int jt=0;jt<2;jt++)
      #pragma unroll
      for(int et=0;et<4;et++) acc[jt][et]=fz;
    int jb = jc*128 + w*32;
    #pragma unroll
    for(int km=0;km<8;km++){
      s8v a0 = *(const s8v*)(Uc + (jb+lr)*256 + km*32 + lg*8);
      s8v a1 = *(const s8v*)(Uc + (jb+16+lr)*256 + km*32 + lg*8);
      #pragma unroll
      for(int et=0;et<4;et++){
        s8v bv = *(const s8v*)(KyT + (et*16+lr)*256 + km*32 + lg*8);
        acc[0][et] = MFMA(a0,bv,acc[0][et]);
        acc[1][et] = MFMA(a1,bv,acc[1][et]);
      }
    }
    #pragma unroll
    for(int jt=0;jt<2;jt++){
      #pragma unroll
      for(int et=0;et<4;et++){
        f4 v = acc[jt][et];
        uint2 pk; pk.x = packbf(v.x,v.y); pk.y = packbf(v.z,v.w);
        *(uint2*)&sT1[(et*16+lr)*136 + w*32 + jt*16 + lg*4] = pk;
      }
    }
    __syncthreads();
    #pragma unroll
    for(int kj=0;kj<4;kj++){
      s8v a = *(const s8v*)(KxT + (w*16+lr)*256 + jc*128 + kj*32 + lg*8);
      #pragma unroll
      for(int et=0;et<4;et++){
        s8v bv = *(const s8v*)&sT1[(et*16+lr)*136 + kj*32 + lg*8];
        cacc[et] = MFMA(a,bv,cacc[et]);
      }
    }
    __syncthreads();
  }
  #pragma unroll
  for(int et=0;et<4;et++){
    f4 v = cacc[et];
    uint2 pk; pk.x=packbf(v.x,v.y); pk.y=packbf(v.z,v.w);
    *(uint2*)&sCT[(et*16+lr)*72 + w*16 + lg*4] = pk;
  }
  __syncthreads();
  {
    s8v aF[4][2];
    #pragma unroll
    for(int me=0;me<4;me++)
      #pragma unroll
      for(int kd=0;kd<2;kd++)
        aF[me][kd] = *(const s8v*)&sCT[(me*16+lr)*72 + kd*32 + lg*8];
    #pragma unroll
    for(int it=0;it<4;it++){
      s8v b0 = *(const s8v*)(Qx + (w*64+it*16+lr)*64 + lg*8);
      s8v b1 = *(const s8v*)(Qx + (w*64+it*16+lr)*64 + 32 + lg*8);
      #pragma unroll
      for(int me=0;me<4;me++){
        f4 pv = MFMA(aF[me][0], b0, fz);
        pv = MFMA(aF[me][1], b1, pv);
        uint2 pk; pk.x=packbf(pv.x,pv.y); pk.y=packbf(pv.z,pv.w);
        *(uint2*)&sP[(w*64+it*16+lr)*72 + me*16 + lg*4] = pk;
      }
    }
  }
  __syncthreads();
  float lsum=0.f, lssq=0.f;
  {
    s8v aP[4][2];
    #pragma unroll
    for(int it=0;it<4;it++)
      #pragma unroll
      for(int ke=0;ke<2;ke++)
        aP[it][ke] = *(const s8v*)&sP[(w*64+it*16+lr)*72 + ke*32 + lg*8];
    for(int lt=0;lt<4;lt++){
      s8v bq[4][2];
      #pragma unroll
      for(int nt=0;nt<4;nt++)
        #pragma unroll
        for(int ke=0;ke<2;ke++)
          bq[nt][ke] = *(const s8v*)(Qy + (lt*64+nt*16+lr)*64 + ke*32 + lg*8);
      #pragma unroll
      for(int it=0;it<4;it++){
        #pragma unroll
        for(int nt=0;nt<4;nt++){
          f4 o = MFMA(aP[it][0], bq[nt][0], fz);
          o = MFMA(aP[it][1], bq[nt][1], o);
          #pragma unroll
          for(int r=0;r<4;r++){
            float val = o[r];
            lsum += val; lssq += val*val;
            out_c[(size_t)(w*64 + it*16 + lg*4 + r)*256 + lt*64 + nt*16 + lr] = f2bf(val);
          }
        }
      }
    }
  }
  float a1 = wave_sum(lsum), a2 = wave_sum(lssq);
  if(lane==0){ sRed[w]=a1; sRed[4+w]=a2; }
  __syncthreads();
  if(t==0){
    float S = sRed[0]+sRed[1]+sRed[2]+sRed[3];
    float SS = sRed[4]+sRed[5]+sRed[6]+sRed[7];
    float m = S*(1.f/65536.f);
    float var = SS*(1.f/65536.f) - m*m;
    istat[(b*128+ch)*2] = m;
    istat[(b*128+ch)*2+1] = rsqrtf(var + EPS_);
  }
}

// ---------------- KF: MFMA InstanceNorm(folded)+conv1-GELU-conv2+residual ----------------
// grid 2048: b = blk>>9, pix tile of 128
__global__ __launch_bounds__(256) void kf_out(
    const ushort_t* __restrict__ up2, const ushort_t* __restrict__ W1b,
    const float* __restrict__ bias1, const ushort_t* __restrict__ w2b,
    const float* __restrict__ u, float* __restrict__ out){
  int blk = blockIdx.x;
  int b = blk>>9; int pix0 = (blk&511)<<7;
  __shared__ __align__(16) unsigned char smraw[128*132*2];
  ushort_t* sX = (ushort_t*)smraw;   // [128ch][132]
  ushort_t* sG = (ushort_t*)smraw;   // [64hid][132] (reuse after sync)
  float* sO = (float*)smraw;         // [64oc][132] f32 (reuse after sync)
  int t = threadIdx.x; int lane = t&63; int w = t>>6; int lr = lane&15; int lg = lane>>4;
  // stage up2 tile
  {
    int ch = t>>4; int px = (t&15)*8;
    #pragma unroll
    for(int it=0; it<8; it++){
      int c = it*16 + ch;
      uint4 v = *(const uint4*)(up2 + ((size_t)(b*128+c))*NPIX + pix0 + px);
      uint2 lo; lo.x = v.x; lo.y = v.y;
      uint2 hi; hi.x = v.z; hi.y = v.w;
      *(uint2*)&sX[c*132 + px] = lo;
      *(uint2*)&sX[c*132 + px + 4] = hi;
    }
  }
  __syncthreads();
  // GEMM1: D1[pix 128][hid 64], K=128ch
  const ushort_t* w1p = W1b + (size_t)b*64*128;
  f4 g[2][4];
  #pragma unroll
  for(int it=0;it<2;it++)
    #pragma unroll
    for(int nt=0;nt<4;nt++){
      float bv = -bias1[b*64 + nt*16 + lr];
      f4 ci = {bv,bv,bv,bv};
      g[it][nt] = ci;
    }
  #pragma unroll
  for(int kc=0;kc<4;kc++){
    s8v bf[4];
    #pragma unroll
    for(int nt=0;nt<4;nt++)
      bf[nt] = *(const s8v*)(w1p + (nt*16+lr)*128 + kc*32 + lg*8);
    #pragma unroll
    for(int it=0;it<2;it++){
      int pix = w*32 + it*16 + lr;
      s8v a;
      #pragma unroll
      for(int j=0;j<8;j++) a[j] = (short)sX[(kc*32+lg*8+j)*132 + pix];
      #pragma unroll
      for(int nt=0;nt<4;nt++)
        g[it][nt] = MFMA(a, bf[nt], g[it][nt]);
    }
  }
  // GELU (erf)
  #pragma unroll
  for(int it=0;it<2;it++)
    #pragma unroll
    for(int nt=0;nt<4;nt++){
      f4 v = g[it][nt];
      #pragma unroll
      for(int r=0;r<4;r++){
        float x = v[r];
        v[r] = 0.5f*x*(1.f + erff(x*0.70710678118654752f));
      }
      g[it][nt] = v;
    }
  __syncthreads();   // all sX reads done
  // write sG[64hid][132]
  #pragma unroll
  for(int it=0;it<2;it++)
    #pragma unroll
    for(int nt=0;nt<4;nt++){
      f4 v = g[it][nt];
      uint2 pk; pk.x = packbf(v.x,v.y); pk.y = packbf(v.z,v.w);
      *(uint2*)&sG[(nt*16+lr)*132 + w*32 + it*16 + lg*4] = pk;
    }
  __syncthreads();
  // GEMM2: D2[pix][oc 64], K=64hid
  f4 o2[2][4];
  const f4 fz = {0.f,0.f,0.f,0.f};
  #pragma unroll
  for(int it=0;it<2;it++)
    #pragma unroll
    for(int nt=0;nt<4;nt++) o2[it][nt]=fz;
  #pragma unroll
  for(int kc=0;kc<2;kc++){
    s8v bf[4];
    #pragma unroll
    for(int nt=0;nt<4;nt++)
      bf[nt] = *(const s8v*)(w2b + (nt*16+lr)*64 + kc*32 + lg*8);
    #pragma unroll
    for(int it=0;it<2;it++){
      int pix = w*32 + it*16 + lr;
      s8v a;
      #pragma unroll
      for(int j=0;j<8;j++) a[j] = (short)sG[(kc*32+lg*8+j)*132 + pix];
      #pragma unroll
      for(int nt=0;nt<4;nt++)
        o2[it][nt] = MFMA(a, bf[nt], o2[it][nt]);
    }
  }
  __syncthreads();  // sG reads done
  // write sO f32 [64oc][132]
  #pragma unroll
  for(int it=0;it<2;it++)
    #pragma unroll
    for(int nt=0;nt<4;nt++)
      *(f4*)&sO[(nt*16+lr)*132 + w*32 + it*16 + lg*4] = o2[it][nt];
  __syncthreads();
  // residual + coalesced store
  {
    int oc = t>>5; int px = (t&31)*4;
    #pragma unroll
    for(int it=0;it<8;it++){
      int o = it*8 + oc;
      float4 ov = *(const float4*)&sO[o*132 + px];
      float4 uv = *(const float4*)(u + ((size_t)(b*64+o))*NPIX + pix0 + px);
      float4 rv;
      rv.x = ov.x+uv.x; rv.y = ov.y+uv.y; rv.z = ov.z+uv.z; rv.w = ov.w+uv.w;
      *(float4*)(out + ((size_t)(b*64+o))*NPIX + pix0 + px) = rv;
    }
  }
}

// ---------------- host launch ----------------
extern "C" void kernel_launch(void* const* d_in, const int* in_sizes, int n_in,
                              void* d_out, int out_size, void* d_ws, size_t ws_size,
                              hipStream_t stream) {
  (void)in_sizes; (void)n_in; (void)out_size; (void)ws_size;
  const float* u        = (const float*)d_in[0];
  const float* gnw      = (const float*)d_in[1];
  const float* gnb      = (const float*)d_in[2];
  const float* w_in_proj= (const float*)d_in[3];
  const float* w_to_in  = (const float*)d_in[4];
  const float* px_win   = (const float*)d_in[5];
  const float* px_ln_g  = (const float*)d_in[6];
  const float* px_ln_b  = (const float*)d_in[7];
  const float* px_w1    = (const float*)d_in[8];
  const float* px_w2    = (const float*)d_in[9];
  const float* px_b2    = (const float*)d_in[10];
  const float* py_win   = (const float*)d_in[11];
  const float* py_ln_g  = (const float*)d_in[12];
  const float* py_ln_b  = (const float*)d_in[13];
  const float* py_w1    = (const float*)d_in[14];
  const float* py_w2    = (const float*)d_in[15];
  const float* py_b2    = (const float*)d_in[16];
  const float* kx_wqk   = (const float*)d_in[17];
  const float* ky_wqk   = (const float*)d_in[18];
  const float* out_w1   = (const float*)d_in[19];
  const float* out_w2   = (const float*)d_in[20];
  float* out = (float*)d_out;

  float* fw = (float*)d_ws;
  float* part  = fw + 0;        // 2048
  float* gnmv  = fw + 2048;     // 8
  float* pc    = fw + 4096;     // 262144 (overlaid by qxb/kxTb after k2b/k3)
  float* poolx = fw + 266240;   // 65536
  float* pooly = fw + 331776;   // 65536
  float* ux    = fw + 397312;   // 131072
  float* uy    = fw + 528384;   // 131072
  float* istat = fw + 659456;   // 1024
  float* c0g   = fw + 660480;   // 512
  float* bias1 = fw + 660992;   // 256
  ushort_t* wpb = (ushort_t*)(fw + 661504);  // 32768 bf16
  ushort_t* W1b = (ushort_t*)(fw + 677888);  // 32768 bf16
  ushort_t* w2b = (ushort_t*)(fw + 694272);  // 4096 bf16
  ushort_t* qxb  = (ushort_t*)(fw + 4096);    // overlay pc
  ushort_t* kxTb = (ushort_t*)(fw + 135168);  // overlay pc
  ushort_t* qyb  = (ushort_t*)(fw + 696320);
  ushort_t* kyTb = (ushort_t*)(fw + 827392);
  ushort_t* up2  = (ushort_t*)(fw + 958464);
  ushort_t* phi = (ushort_t*)d_out;  // u_phi staged in d_out, consumed by k7 before kf writes out

  k1_stats<<<dim3(1024), dim3(256), 0, stream>>>(u, part, pc, poolx);
  k2_fin<<<dim3(1), dim3(256), 0, stream>>>(part, gnmv);
  k2b_pool<<<dim3(256), dim3(256), 0, stream>>>(pc, pooly);
  k8a_fold<<<dim3(4), dim3(256), 0, stream>>>(gnmv, gnw, gnb, w_in_proj, out_w2, wpb, c0g, w2b);
  k3_reduce<<<dim3(2048), dim3(128), 0, stream>>>(poolx, pooly, gnmv, gnw, gnb, w_to_in,
      px_win, px_ln_g, px_ln_b, px_w1, px_w2, px_b2,
      py_win, py_ln_g, py_ln_b, py_w1, py_w2, py_b2, ux, uy);
  k4_qkrope<<<dim3(2048), dim3(128), 0, stream>>>(ux, uy, kx_wqk, ky_wqk, qxb, kxTb, qyb, kyTb);
  k6_phi<<<dim3(2048), dim3(256), 0, stream>>>(u, wpb, c0g, phi);
  k7_heavy<<<dim3(512), dim3(256), 0, stream>>>(phi, qxb, kxTb, qyb, kyTb, up2, istat);
  k8b_fold<<<dim3(4), dim3(64), 0, stream>>>(istat, out_w1, W1b, bias1);
  kf_out<<<dim3(2048), dim3(256), 0, stream>>>(up2, W1b, bias1, w2b, u, out);
}

// Round 4
// 206.560 us; speedup vs baseline: 3.1545x; 1.2500x over previous
//
#include <hip/hip_runtime.h>
#include <math.h>

typedef unsigned short ushort_t;
typedef unsigned int uint_t;
typedef __attribute__((ext_vector_type(8))) short s8v;
typedef __attribute__((ext_vector_type(4))) float f4;

#define NPIX 65536
#define EPS_ 1e-5f

__device__ __forceinline__ float bf2f(ushort_t u){ return __uint_as_float(((uint_t)u)<<16); }
__device__ __forceinline__ ushort_t f2bf(float f){
  uint_t u = __float_as_uint(f);
  uint_t r = (u + 0x7fffu + ((u>>16)&1u)) >> 16;
  return (ushort_t)r;
}
__device__ __forceinline__ uint_t packbf(float a, float b){ return (uint_t)f2bf(a) | ((uint_t)f2bf(b)<<16); }

__device__ __forceinline__ f4 MFMA(s8v a, s8v b, f4 c){
  return __builtin_amdgcn_mfma_f32_16x16x32_bf16(a, b, c, 0, 0, 0);
}

__device__ __forceinline__ float wave_sum(float v){
  #pragma unroll
  for(int m=32;m>=1;m>>=1) v += __shfl_xor(v, m, 64);
  return v;
}

// ---------------- K1: GN partial sums + partial col sums + row pools ----------------
__global__ __launch_bounds__(256) void k1_stats(const float* __restrict__ u,
    float* __restrict__ part, float* __restrict__ pc, float* __restrict__ poolx){
  int blk = blockIdx.x; int b = blk>>8; int c = (blk>>2)&63; int iq = blk&3;
  int t = threadIdx.x; int lane = t&63; int w = t>>6;
  const float* up = u + ((size_t)(b*64+c))*NPIX + iq*64*256;
  __shared__ float red[8];
  float cs=0.f, ss=0.f;
  for(int r=0;r<64;r++){
    float v = up[r*256 + t];
    cs += v; ss += v*v;
  }
  pc[((b*64+c)*4 + iq)*256 + t] = cs;
  float a1 = wave_sum(cs), a2 = wave_sum(ss);
  if(lane==0){ red[w]=a1; red[4+w]=a2; }
  __syncthreads();
  if(t==0){
    part[((b*64+c)*4+iq)*2]   = red[0]+red[1]+red[2]+red[3];
    part[((b*64+c)*4+iq)*2+1] = red[4]+red[5]+red[6]+red[7];
  }
  int r = t>>2, ck = t&3;
  const float* rp = up + r*256 + ck*64;
  float s=0.f;
  #pragma unroll 4
  for(int j=0;j<16;j++){
    float4 v4 = *(const float4*)(rp + j*4);
    s += v4.x + v4.y + v4.z + v4.w;
  }
  s += __shfl_xor(s, 1, 64);
  s += __shfl_xor(s, 2, 64);
  if(ck==0) poolx[(b*256 + iq*64 + r)*64 + c] = s * (1.f/256.f);
}

// ---------------- K2: finalize GroupNorm mean/rstd ----------------
__global__ void k2_fin(const float* __restrict__ part, float* __restrict__ gnmv){
  int t = threadIdx.x; int b = t>>6; int i = t&63;
  float S1=0.f, S2=0.f;
  #pragma unroll
  for(int q=0;q<4;q++){
    S1 += part[((b*64+i)*4+q)*2];
    S2 += part[((b*64+i)*4+q)*2+1];
  }
  S1 = wave_sum(S1); S2 = wave_sum(S2);
  if(i==0){
    const float inv = 1.f/4194304.f;
    float m = S1*inv; float v = S2*inv - m*m;
    gnmv[b*2] = m; gnmv[b*2+1] = rsqrtf(v + EPS_);
  }
}

// ---------------- K2b: finalize pooly ----------------
__global__ __launch_bounds__(256) void k2b_pool(const float* __restrict__ pc,
    float* __restrict__ pooly){
  int blk = blockIdx.x; int b = blk>>6; int c = blk&63;
  int t = threadIdx.x;
  const float* p = pc + ((size_t)(b*64+c))*4*256 + t;
  float s = p[0] + p[256] + p[512] + p[768];
  pooly[(b*256+t)*64 + c] = s * (1.f/256.f);
}

// ---------------- K8a: fold GN into w_in_proj + w2 bf16 ----------------
__global__ __launch_bounds__(256) void k8a_fold(const float* __restrict__ gnmv,
    const float* __restrict__ gnw, const float* __restrict__ gnb,
    const float* __restrict__ w_in_proj, const float* __restrict__ out_w2,
    ushort_t* __restrict__ wpb, float* __restrict__ c0g, ushort_t* __restrict__ w2b){
  int b = blockIdx.x; int t = threadIdx.x;
  __shared__ float scs[64], shs[64];
  if(t<64){
    float mean = gnmv[b*2], rstd = gnmv[b*2+1];
    float sc = rstd*gnw[t];
    scs[t] = sc; shs[t] = gnb[t] - mean*sc;
  }
  __syncthreads();
  int oc = t>>1, h = t&1;
  float c0 = 0.f;
  for(int k=0;k<32;k++){
    int ch = h*32 + k;
    float wv = w_in_proj[oc*64 + ch];
    wpb[((size_t)b*128 + oc)*64 + ch] = f2bf(wv*scs[ch]);
    c0 += wv*shs[ch];
  }
  c0 += __shfl_xor(c0, 1, 64);
  if(h==0) c0g[b*128 + oc] = c0;
  if(b==0){
    for(int e=t;e<4096;e+=256) w2b[e] = f2bf(out_w2[e]);
  }
}

// ---------------- K8b: fold InstanceNorm into out_w1 ----------------
__global__ void k8b_fold(const float* __restrict__ istat,
    const float* __restrict__ out_w1, ushort_t* __restrict__ W1b,
    float* __restrict__ bias1){
  int b = blockIdx.x; int t = threadIdx.x;
  __shared__ float ms[128], rss[128];
  ms[t] = istat[(b*128+t)*2];       rss[t] = istat[(b*128+t)*2+1];
  ms[64+t] = istat[(b*128+64+t)*2]; rss[64+t] = istat[(b*128+64+t)*2+1];
  __syncthreads();
  float bias = 0.f;
  for(int ch=0;ch<128;ch++){
    float wv = out_w1[t*128 + ch];
    float wr = wv*rss[ch];
    W1b[((size_t)b*64 + t)*128 + ch] = f2bf(wr);
    bias += wr*ms[ch];
  }
  bias1[b*64 + t] = bias;
}

// ---------------- K3: pooled path -> reducer ----------------
__global__ __launch_bounds__(128) void k3_reduce(
    const float* __restrict__ poolx, const float* __restrict__ pooly,
    const float* __restrict__ gnmv,
    const float* __restrict__ gnw, const float* __restrict__ gnb,
    const float* __restrict__ w_to_in,
    const float* __restrict__ xwin, const float* __restrict__ xlg, const float* __restrict__ xlb,
    const float* __restrict__ xw1, const float* __restrict__ xw2, const float* __restrict__ xb2,
    const float* __restrict__ ywin, const float* __restrict__ ylg, const float* __restrict__ ylb,
    const float* __restrict__ yw1, const float* __restrict__ yw2, const float* __restrict__ yb2,
    float* __restrict__ ux, float* __restrict__ uy){
  int id = blockIdx.x;
  int side = id >> 10; int r = id & 1023; int b = r>>8; int i = r&255;
  const float* pool = side ? pooly : poolx;
  const float* win = side ? ywin : xwin;
  const float* lg  = side ? ylg  : xlg;
  const float* lb  = side ? ylb  : xlb;
  const float* w1  = side ? yw1  : xw1;
  const float* w2  = side ? yw2  : xw2;
  const float* b2  = side ? yb2  : xb2;
  float* outp = side ? uy : ux;
  int t = threadIdx.x;
  __shared__ float pn[64], t1[64], hh[64], f1[128];
  float mean = gnmv[b*2], rstd = gnmv[b*2+1];
  if(t<64){
    float pv = pool[(b*256+i)*64 + t];
    pn[t] = (pv - mean)*rstd*gnw[t] + gnb[t];
  }
  __syncthreads();
  if(t<64){
    float acc=0.f; const float* wr = w_to_in + t*64;
    #pragma unroll 8
    for(int c=0;c<64;c++) acc += pn[c]*wr[c];
    t1[t]=acc;
  }
  __syncthreads();
  if(t<64){
    float acc=0.f; const float* wr = win + t*64;
    #pragma unroll 8
    for(int c=0;c<64;c++) acc += t1[c]*wr[c];
    hh[t]=acc;
  }
  __syncthreads();
  if(t<64){
    float v = hh[t];
    float s = wave_sum(v);
    float ss = wave_sum(v*v);
    float m2 = s*(1.f/64.f);
    float var = ss*(1.f/64.f) - m2*m2;
    float rs2 = rsqrtf(var + EPS_);
    hh[t] = (v - m2)*rs2*lg[t] + lb[t];
  }
  __syncthreads();
  {
    float acc=0.f; const float* wr = w1 + t*64;
    #pragma unroll 8
    for(int c=0;c<64;c++) acc += hh[c]*wr[c];
    f1[t] = 0.5f*acc*(1.f + erff(acc*0.70710678118654752f));
  }
  __syncthreads();
  {
    float acc=0.f; const float* wr = w2 + t*128;
    #pragma unroll 8
    for(int j=0;j<128;j++) acc += f1[j]*wr[j];
    outp[(b*256+i)*128 + t] = acc + b2[t];
  }
}

// ---------------- K4: MFMA qk GEMM + fused RoPE ----------------
// grid 64: side(1b) | b(2b) | mt(1b) | nt(2b). M=128 tokens, N=128 outs, K=128.
__global__ __launch_bounds__(256) void k4_gemm(
    const float* __restrict__ ux, const float* __restrict__ uy,
    const float* __restrict__ wqkx, const float* __restrict__ wqky,
    ushort_t* __restrict__ qxb, ushort_t* __restrict__ kxTb,
    ushort_t* __restrict__ qyb, ushort_t* __restrict__ kyTb){
  int blk = blockIdx.x;
  int nt = blk&3; int mt = (blk>>2)&1; int b = (blk>>3)&3; int side = blk>>5;
  const float* x  = (side? uy:ux) + (size_t)(b*256 + mt*128)*128;
  const float* wq = (side? wqky:wqkx) + (size_t)nt*128*128;
  ushort_t* qb  = side? qyb : qxb;
  ushort_t* kTb = side? kyTb : kxTb;

  __shared__ __align__(16) ushort_t sA[128*136];  // tokens [i][c] bf16 (reused as kT tile)
  __shared__ __align__(16) ushort_t sB[128*136];  // weights [o][c] bf16

  int t = threadIdx.x; int lane = t&63; int w = t>>6; int lr = lane&15; int lg = lane>>4;
  // stage x and w (f32 -> bf16), coalesced
  for(int e=t;e<4096;e+=256){
    int row = e>>5, c4 = (e&31)*4;
    float4 v = *(const float4*)(x + row*128 + c4);
    uint2 pk; pk.x = packbf(v.x,v.y); pk.y = packbf(v.z,v.w);
    *(uint2*)&sA[row*136 + c4] = pk;
    float4 wv = *(const float4*)(wq + row*128 + c4);
    uint2 wk; wk.x = packbf(wv.x,wv.y); wk.y = packbf(wv.z,wv.w);
    *(uint2*)&sB[row*136 + c4] = wk;
  }
  __syncthreads();
  // MFMA: wave w owns token rows [w*32, +32)
  const f4 fz = {0.f,0.f,0.f,0.f};
  f4 acc[2][8];
  #pragma unroll
  for(int it=0;it<2;it++)
    #pragma unroll
    for(int n2=0;n2<8;n2++) acc[it][n2]=fz;
  #pragma unroll
  for(int kc=0;kc<4;kc++){
    s8v bf[8];
    #pragma unroll
    for(int n2=0;n2<8;n2++)
      bf[n2] = *(const s8v*)&sB[(n2*16+lr)*136 + kc*32 + lg*8];
    #pragma unroll
    for(int it=0;it<2;it++){
      s8v a = *(const s8v*)&sA[(w*32+it*16+lr)*136 + kc*32 + lg*8];
      #pragma unroll
      for(int n2=0;n2<8;n2++)
        acc[it][n2] = MFMA(a, bf[n2], acc[it][n2]);
    }
  }
  // RoPE epilogue. o = nt*128 + n2*16 + lr; token i = mt*128 + w*32 + it*16 + lg*4 + r.
  if(nt < 2){
    // q outputs: direct scatter store (h = o>>6, dd = o&63)
    #pragma unroll
    for(int it=0;it<2;it++){
      #pragma unroll
      for(int n2=0;n2<8;n2++){
        int o = nt*128 + n2*16 + lr;
        int h = o>>6, dd = o&63, t32 = dd&31;
        float invf = expf(-(float)t32*(9.210340371976184f/32.f));
        size_t base = (size_t)(b*4+h)*16384;
        #pragma unroll
        for(int r=0;r<4;r++){
          int i = mt*128 + w*32 + it*16 + lg*4 + r;
          float f = (64.f/255.f)*(float)i*invf;
          float sn, cs; __sincosf(f, &sn, &cs);
          float pair = acc[it][n2^2][r];
          float rot = ((n2&2)==0)? -pair : pair;
          float v = acc[it][n2][r]*cs + rot*sn;
          qb[base + (size_t)i*64 + dd] = f2bf(v);
        }
      }
    }
  } else {
    // k outputs: transpose via LDS (reuse sA), then coalesced kT[dd][i] writes
    __syncthreads();  // all MFMA reads of sA done
    #pragma unroll
    for(int it=0;it<2;it++){
      #pragma unroll
      for(int n2=0;n2<8;n2++){
        int ol = n2*16 + lr;
        int o = nt*128 + ol;
        int t32 = o&31;
        float invf = expf(-(float)t32*(9.210340371976184f/32.f));
        #pragma unroll
        for(int r=0;r<4;r++){
          int il = w*32 + it*16 + lg*4 + r;
          int i = mt*128 + il;
          float f = (64.f/255.f)*(float)i*invf;
          float sn, cs; __sincosf(f, &sn, &cs);
          float pair = acc[it][n2^2][r];
          float rot = ((n2&2)==0)? -pair : pair;
          float v = acc[it][n2][r]*cs + rot*sn;
          sA[ol*136 + il] = f2bf(v);
        }
      }
    }
    __syncthreads();
    // row ol: h = (nt-2)*2 + (ol>>6), dd = ol&63; dst row = kTb + bh*16384 + dd*256 + mt*128
    {
      int row = t>>1, half = t&1;
      int h = (nt-2)*2 + (row>>6), dd = row&63;
      ushort_t* dst = kTb + (size_t)(b*4+h)*16384 + (size_t)dd*256 + mt*128 + half*64;
      const ushort_t* src = &sA[row*136 + half*64];
      #pragma unroll
      for(int j=0;j<8;j++)
        *(uint4*)(dst + j*8) = *(const uint4*)(src + j*8);
    }
  }
}

// ---------------- K6: MFMA 1x1 conv u -> u_phi ----------------
__global__ __launch_bounds__(256) void k6_phi(
    const float* __restrict__ u, const ushort_t* __restrict__ wpb,
    const float* __restrict__ c0g, ushort_t* __restrict__ phi){
  int blk = blockIdx.x;
  int b = blk>>9; int pix0 = (blk&511)<<7;
  __shared__ __align__(16) ushort_t sm[128*136];
  int t = threadIdx.x; int lane = t&63; int w = t>>6; int lr = lane&15; int lg = lane>>4;
  {
    int ch = t>>5; int px = (t&31)*4;
    #pragma unroll
    for(int it=0; it<8; it++){
      int c = it*8 + ch;
      float4 v = *(const float4*)(u + ((size_t)(b*64+c))*NPIX + pix0 + px);
      uint2 pk; pk.x = packbf(v.x, v.y); pk.y = packbf(v.z, v.w);
      *(uint2*)&sm[c*132 + px] = pk;
    }
  }
  __syncthreads();
  const ushort_t* wb = wpb + (size_t)b*128*64;
  f4 acc[2][8];
  #pragma unroll
  for(int it=0;it<2;it++)
    #pragma unroll
    for(int nt=0;nt<8;nt++){
      float cv = c0g[b*128 + nt*16 + lr];
      f4 ci = {cv,cv,cv,cv};
      acc[it][nt] = ci;
    }
  #pragma unroll
  for(int kc=0;kc<2;kc++){
    s8v bf[8];
    #pragma unroll
    for(int nt=0;nt<8;nt++)
      bf[nt] = *(const s8v*)(wb + (nt*16+lr)*64 + kc*32 + lg*8);
    #pragma unroll
    for(int it=0;it<2;it++){
      int pix = w*32 + it*16 + lr;
      s8v a;
      #pragma unroll
      for(int j=0;j<8;j++) a[j] = (short)sm[(kc*32+lg*8+j)*132 + pix];
      #pragma unroll
      for(int nt=0;nt<8;nt++)
        acc[it][nt] = MFMA(a, bf[nt], acc[it][nt]);
    }
  }
  __syncthreads();
  #pragma unroll
  for(int it=0;it<2;it++)
    #pragma unroll
    for(int nt=0;nt<8;nt++){
      f4 v = acc[it][nt];
      uint2 pk; pk.x = packbf(v.x,v.y); pk.y = packbf(v.z,v.w);
      *(uint2*)&sm[(nt*16+lr)*136 + w*32 + it*16 + lg*4] = pk;
    }
  __syncthreads();
  {
    int oc = t>>4; int px = (t&15)*8;
    #pragma unroll
    for(int it=0;it<8;it++){
      int o = it*16 + oc;
      *(uint4*)(phi + ((size_t)(b*128+o))*NPIX + pix0 + px) = *(const uint4*)&sm[o*136 + px];
    }
  }
}

// ---------------- K7: MFMA low-rank double contraction per (b,h,c) ----------------
__global__ __launch_bounds__(256) void k7_heavy(
    const ushort_t* __restrict__ phi,
    const ushort_t* __restrict__ qxb, const ushort_t* __restrict__ kxTb,
    const ushort_t* __restrict__ qyb, const ushort_t* __restrict__ kyTb,
    ushort_t* __restrict__ up2, float* __restrict__ istat){
  int blk = blockIdx.x;
  int c = blk & 31; int h = (blk>>5)&3; int b = blk>>7;
  int bh = b*4 + h; int ch = h*32 + c;
  const ushort_t* Uc  = phi + (size_t)(b*128 + ch)*NPIX;
  const ushort_t* KxT = kxTb + (size_t)bh*16384;
  const ushort_t* KyT = kyTb + (size_t)bh*16384;
  const ushort_t* Qx  = qxb + (size_t)bh*16384;
  const ushort_t* Qy  = qyb + (size_t)bh*16384;
  ushort_t* out_c = up2 + (size_t)(b*128 + ch)*NPIX;

  __shared__ __align__(16) ushort_t sT1[64*136];
  __shared__ __align__(16) ushort_t sCT[64*72];
  __shared__ __align__(16) ushort_t sP[256*72];
  __shared__ float sRed[8];

  int t = threadIdx.x; int w = t>>6; int lane = t&63; int lr = lane&15; int lg = lane>>4;
  const f4 fz = {0.f,0.f,0.f,0.f};
  f4 cacc[4];
  #pragma unroll
  for(int et=0;et<4;et++) cacc[et]=fz;

  for(int jc=0;jc<2;jc++){
    f4 acc[2][4];
    #pragma unroll
    for(int jt=0;jt<2;jt++)
      #pragma unroll
      for(int et=0;et<4;et++) acc[jt][et]=fz;
    int jb = jc*128 + w*32;
    #pragma unroll
    for(int km=0;km<8;km++){
      s8v a0 = *(const s8v*)(Uc + (jb+lr)*256 + km*32 + lg*8);
      s8v a1 = *(const s8v*)(Uc + (jb+16+lr)*256 + km*32 + lg*8);
      #pragma unroll
      for(int et=0;et<4;et++){
        s8v bv = *(const s8v*)(KyT + (et*16+lr)*256 + km*32 + lg*8);
        acc[0][et] = MFMA(a0,bv,acc[0][et]);
        acc[1][et] = MFMA(a1,bv,acc[1][et]);
      }
    }
    #pragma unroll
    for(int jt=0;jt<2;jt++){
      #pragma unroll
      for(int et=0;et<4;et++){
        f4 v = acc[jt][et];
        uint2 pk; pk.x = packbf(v.x,v.y); pk.y = packbf(v.z,v.w);
        *(uint2*)&sT1[(et*16+lr)*136 + w*32 + jt*16 + lg*4] = pk;
      }
    }
    __syncthreads();
    #pragma unroll
    for(int kj=0;kj<4;kj++){
      s8v a = *(const s8v*)(KxT + (w*16+lr)*256 + jc*128 + kj*32 + lg*8);
      #pragma unroll
      for(int et=0;et<4;et++){
        s8v bv = *(const s8v*)&sT1[(et*16+lr)*136 + kj*32 + lg*8];
        cacc[et] = MFMA(a,bv,cacc[et]);
      }
    }
    __syncthreads();
  }
  #pragma unroll
  for(int et=0;et<4;et++){
    f4 v = cacc[et];
    uint2 pk; pk.x=packbf(v.x,v.y); pk.y=packbf(v.z,v.w);
    *(uint2*)&sCT[(et*16+lr)*72 + w*16 + lg*4] = pk;
  }
  __syncthreads();
  {
    s8v aF[4][2];
    #pragma unroll
    for(int me=0;me<4;me++)
      #pragma unroll
      for(int kd=0;kd<2;kd++)
        aF[me][kd] = *(const s8v*)&sCT[(me*16+lr)*72 + kd*32 + lg*8];
    #pragma unroll
    for(int it=0;it<4;it++){
      s8v b0 = *(const s8v*)(Qx + (w*64+it*16+lr)*64 + lg*8);
      s8v b1 = *(const s8v*)(Qx + (w*64+it*16+lr)*64 + 32 + lg*8);
      #pragma unroll
      for(int me=0;me<4;me++){
        f4 pv = MFMA(aF[me][0], b0, fz);
        pv = MFMA(aF[me][1], b1, pv);
        uint2 pk; pk.x=packbf(pv.x,pv.y); pk.y=packbf(pv.z,pv.w);
        *(uint2*)&sP[(w*64+it*16+lr)*72 + me*16 + lg*4] = pk;
      }
    }
  }
  __syncthreads();
  float lsum=0.f, lssq=0.f;
  {
    s8v aP[4][2];
    #pragma unroll
    for(int it=0;it<4;it++)
      #pragma unroll
      for(int ke=0;ke<2;ke++)
        aP[it][ke] = *(const s8v*)&sP[(w*64+it*16+lr)*72 + ke*32 + lg*8];
    for(int lt=0;lt<4;lt++){
      s8v bq[4][2];
      #pragma unroll
      for(int nt=0;nt<4;nt++)
        #pragma unroll
        for(int ke=0;ke<2;ke++)
          bq[nt][ke] = *(const s8v*)(Qy + (lt*64+nt*16+lr)*64 + ke*32 + lg*8);
      #pragma unroll
      for(int it=0;it<4;it++){
        #pragma unroll
        for(int nt=0;nt<4;nt++){
          f4 o = MFMA(aP[it][0], bq[nt][0], fz);
          o = MFMA(aP[it][1], bq[nt][1], o);
          #pragma unroll
          for(int r=0;r<4;r++){
            float val = o[r];
            lsum += val; lssq += val*val;
            out_c[(size_t)(w*64 + it*16 + lg*4 + r)*256 + lt*64 + nt*16 + lr] = f2bf(val);
          }
        }
      }
    }
  }
  float a1 = wave_sum(lsum), a2 = wave_sum(lssq);
  if(lane==0){ sRed[w]=a1; sRed[4+w]=a2; }
  __syncthreads();
  if(t==0){
    float S = sRed[0]+sRed[1]+sRed[2]+sRed[3];
    float SS = sRed[4]+sRed[5]+sRed[6]+sRed[7];
    float m = S*(1.f/65536.f);
    float var = SS*(1.f/65536.f) - m*m;
    istat[(b*128+ch)*2] = m;
    istat[(b*128+ch)*2+1] = rsqrtf(var + EPS_);
  }
}

// ---------------- KF: MFMA InstanceNorm(folded)+conv1-GELU-conv2+residual ----------------
__global__ __launch_bounds__(256) void kf_out(
    const ushort_t* __restrict__ up2, const ushort_t* __restrict__ W1b,
    const float* __restrict__ bias1, const ushort_t* __restrict__ w2b,
    const float* __restrict__ u, float* __restrict__ out){
  int blk = blockIdx.x;
  int b = blk>>9; int pix0 = (blk&511)<<7;
  __shared__ __align__(16) unsigned char smraw[128*132*2];
  ushort_t* sX = (ushort_t*)smraw;
  ushort_t* sG = (ushort_t*)smraw;
  float* sO = (float*)smraw;
  int t = threadIdx.x; int lane = t&63; int w = t>>6; int lr = lane&15; int lg = lane>>4;
  {
    int ch = t>>4; int px = (t&15)*8;
    #pragma unroll
    for(int it=0; it<8; it++){
      int c = it*16 + ch;
      uint4 v = *(const uint4*)(up2 + ((size_t)(b*128+c))*NPIX + pix0 + px);
      uint2 lo; lo.x = v.x; lo.y = v.y;
      uint2 hi; hi.x = v.z; hi.y = v.w;
      *(uint2*)&sX[c*132 + px] = lo;
      *(uint2*)&sX[c*132 + px + 4] = hi;
    }
  }
  __syncthreads();
  const ushort_t* w1p = W1b + (size_t)b*64*128;
  f4 g[2][4];
  #pragma unroll
  for(int it=0;it<2;it++)
    #pragma unroll
    for(int nt=0;nt<4;nt++){
      float bv = -bias1[b*64 + nt*16 + lr];
      f4 ci = {bv,bv,bv,bv};
      g[it][nt] = ci;
    }
  #pragma unroll
  for(int kc=0;kc<4;kc++){
    s8v bf[4];
    #pragma unroll
    for(int nt=0;nt<4;nt++)
      bf[nt] = *(const s8v*)(w1p + (nt*16+lr)*128 + kc*32 + lg*8);
    #pragma unroll
    for(int it=0;it<2;it++){
      int pix = w*32 + it*16 + lr;
      s8v a;
      #pragma unroll
      for(int j=0;j<8;j++) a[j] = (short)sX[(kc*32+lg*8+j)*132 + pix];
      #pragma unroll
      for(int nt=0;nt<4;nt++)
        g[it][nt] = MFMA(a, bf[nt], g[it][nt]);
    }
  }
  #pragma unroll
  for(int it=0;it<2;it++)
    #pragma unroll
    for(int nt=0;nt<4;nt++){
      f4 v = g[it][nt];
      #pragma unroll
      for(int r=0;r<4;r++){
        float x = v[r];
        v[r] = 0.5f*x*(1.f + erff(x*0.70710678118654752f));
      }
      g[it][nt] = v;
    }
  __syncthreads();
  #pragma unroll
  for(int it=0;it<2;it++)
    #pragma unroll
    for(int nt=0;nt<4;nt++){
      f4 v = g[it][nt];
      uint2 pk; pk.x = packbf(v.x,v.y); pk.y = packbf(v.z,v.w);
      *(uint2*)&sG[(nt*16+lr)*132 + w*32 + it*16 + lg*4] = pk;
    }
  __syncthreads();
  f4 o2[2][4];
  const f4 fz = {0.f,0.f,0.f,0.f};
  #pragma unroll
  for(int it=0;it<2;it++)
    #pragma unroll
    for(int nt=0;nt<4;nt++) o2[it][nt]=fz;
  #pragma unroll
  for(int kc=0;kc<2;kc++){
    s8v bf[4];
    #pragma unroll
    for(int nt=0;nt<4;nt++)
      bf[nt] = *(const s8v*)(w2b + (nt*16+lr)*64 + kc*32 + lg*8);
    #pragma unroll
    for(int it=0;it<2;it++){
      int pix = w*32 + it*16 + lr;
      s8v a;
      #pragma unroll
      for(int j=0;j<8;j++) a[j] = (short)sG[(kc*32+lg*8+j)*132 + pix];
      #pragma unroll
      for(int nt=0;nt<4;nt++)
        o2[it][nt] = MFMA(a, bf[nt], o2[it][nt]);
    }
  }
  __syncthreads();
  #pragma unroll
  for(int it=0;it<2;it++)
    #pragma unroll
    for(int nt=0;nt<4;nt++)
      *(f4*)&sO[(nt*16+lr)*132 + w*32 + it*16 + lg*4] = o2[it][nt];
  __syncthreads();
  {
    int oc = t>>5; int px = (t&31)*4;
    #pragma unroll
    for(int it=0;it<8;it++){
      int o = it*8 + oc;
      float4 ov = *(const float4*)&sO[o*132 + px];
      float4 uv = *(const float4*)(u + ((size_t)(b*64+o))*NPIX + pix0 + px);
      float4 rv;
      rv.x = ov.x+uv.x; rv.y = ov.y+uv.y; rv.z = ov.z+uv.z; rv.w = ov.w+uv.w;
      *(float4*)(out + ((size_t)(b*64+o))*NPIX + pix0 + px) = rv;
    }
  }
}

// ---------------- host launch ----------------
extern "C" void kernel_launch(void* const* d_in, const int* in_sizes, int n_in,
                              void* d_out, int out_size, void* d_ws, size_t ws_size,
                              hipStream_t stream) {
  (void)in_sizes; (void)n_in; (void)out_size; (void)ws_size;
  const float* u        = (const float*)d_in[0];
  const float* gnw      = (const float*)d_in[1];
  const float* gnb      = (const float*)d_in[2];
  const float* w_in_proj= (const float*)d_in[3];
  const float* w_to_in  = (const float*)d_in[4];
  const float* px_win   = (const float*)d_in[5];
  const float* px_ln_g  = (const float*)d_in[6];
  const float* px_ln_b  = (const float*)d_in[7];
  const float* px_w1    = (const float*)d_in[8];
  const float* px_w2    = (const float*)d_in[9];
  const float* px_b2    = (const float*)d_in[10];
  const float* py_win   = (const float*)d_in[11];
  const float* py_ln_g  = (const float*)d_in[12];
  const float* py_ln_b  = (const float*)d_in[13];
  const float* py_w1    = (const float*)d_in[14];
  const float* py_w2    = (const float*)d_in[15];
  const float* py_b2    = (const float*)d_in[16];
  const float* kx_wqk   = (const float*)d_in[17];
  const float* ky_wqk   = (const float*)d_in[18];
  const float* out_w1   = (const float*)d_in[19];
  const float* out_w2   = (const float*)d_in[20];
  float* out = (float*)d_out;

  float* fw = (float*)d_ws;
  float* part  = fw + 0;        // 2048
  float* gnmv  = fw + 2048;     // 8
  float* pc    = fw + 4096;     // 262144 (overlaid by qxb/kxTb after k2b)
  float* poolx = fw + 266240;   // 65536
  float* pooly = fw + 331776;   // 65536
  float* ux    = fw + 397312;   // 131072
  float* uy    = fw + 528384;   // 131072
  float* istat = fw + 659456;   // 1024
  float* c0g   = fw + 660480;   // 512
  float* bias1 = fw + 660992;   // 256
  ushort_t* wpb = (ushort_t*)(fw + 661504);
  ushort_t* W1b = (ushort_t*)(fw + 677888);
  ushort_t* w2b = (ushort_t*)(fw + 694272);
  ushort_t* qxb  = (ushort_t*)(fw + 4096);
  ushort_t* kxTb = (ushort_t*)(fw + 135168);
  ushort_t* qyb  = (ushort_t*)(fw + 696320);
  ushort_t* kyTb = (ushort_t*)(fw + 827392);
  ushort_t* up2  = (ushort_t*)(fw + 958464);
  ushort_t* phi = (ushort_t*)d_out;

  k1_stats<<<dim3(1024), dim3(256), 0, stream>>>(u, part, pc, poolx);
  k2_fin<<<dim3(1), dim3(256), 0, stream>>>(part, gnmv);
  k2b_pool<<<dim3(256), dim3(256), 0, stream>>>(pc, pooly);
  k8a_fold<<<dim3(4), dim3(256), 0, stream>>>(gnmv, gnw, gnb, w_in_proj, out_w2, wpb, c0g, w2b);
  k3_reduce<<<dim3(2048), dim3(128), 0, stream>>>(poolx, pooly, gnmv, gnw, gnb, w_to_in,
      px_win, px_ln_g, px_ln_b, px_w1, px_w2, px_b2,
      py_win, py_ln_g, py_ln_b, py_w1, py_w2, py_b2, ux, uy);
  k4_gemm<<<dim3(64), dim3(256), 0, stream>>>(ux, uy, kx_wqk, ky_wqk, qxb, kxTb, qyb, kyTb);
  k6_phi<<<dim3(2048), dim3(256), 0, stream>>>(u, wpb, c0g, phi);
  k7_heavy<<<dim3(512), dim3(256), 0, stream>>>(phi, qxb, kxTb, qyb, kyTb, up2, istat);
  k8b_fold<<<dim3(4), dim3(64), 0, stream>>>(istat, out_w1, W1b, bias1);
  kf_out<<<dim3(2048), dim3(256), 0, stream>>>(up2, W1b, bias1, w2b, u, out);
}